// Round 8
// baseline (2083.007 us; speedup 1.0000x reference)
//
#include <hip/hip_runtime.h>
#include <stdint.h>

#define NA 200000
#define NB 300000
#define NG 10000
#define DD 256
#define EPS_GATE 1e-6f
#define EPS_BN 1e-5f

typedef short bf16x8 __attribute__((ext_vector_type(8)));
typedef float f32x4 __attribute__((ext_vector_type(4)));

__device__ __forceinline__ unsigned short f2bf(float f){
  union { float f; uint32_t u; } v; v.f = f;
  uint32_t uu = v.u;
  uint32_t r = (uu + 0x7FFFu + ((uu >> 16) & 1u)) >> 16;
  return (unsigned short)r;
}
__device__ __forceinline__ float bf2f(unsigned short s){
  union { uint32_t u; float f; } v; v.u = ((uint32_t)s) << 16; return v.f;
}

__device__ __forceinline__ void gload_lds16(const unsigned short* g, unsigned short* l){
  __builtin_amdgcn_global_load_lds(
      (const __attribute__((address_space(1))) unsigned int*)g,
      (__attribute__((address_space(3))) unsigned int*)l, 16, 0, 0);
}

// ---------------- zero fill ----------------
__global__ void k_zero(int4* p, size_t n16){
  for (size_t i = blockIdx.x*(size_t)blockDim.x + threadIdx.x; i < n16;
       i += (size_t)gridDim.x*blockDim.x)
    p[i] = make_int4(0,0,0,0);
}

// ---------------- W fp32 -> bf16 ----------------
__global__ void k_wconv(const float* __restrict__ W, unsigned short* __restrict__ Wbf, int n4){
  for (int i = blockIdx.x*blockDim.x + threadIdx.x; i < n4; i += gridDim.x*blockDim.x){
    float4 v = ((const float4*)W)[i];
    ushort4 o; o.x = f2bf(v.x); o.y = f2bf(v.y); o.z = f2bf(v.z); o.w = f2bf(v.w);
    ((ushort4*)Wbf)[i] = o;
  }
}

// ====== fused GEMM (R5 structure, HK phase order): Y[jj] = x @ W[j]^T + b[j] ======
// 512 thr (8 waves: wr in {0,1} M-half, wc in {0..3} N-quarter).
// Tile 128 rows x 256 cols; A (full K=256) swizzled bf16 in LDS (64KB), staged once.
// B: one 256x32 slice (16KB), single-buffered via global_load_lds.
// Per K-step: ds_read frags -> barrier(#1, frees Bs) -> issue stage(it+1)
//            -> 16 MFMA (regs only, covers stage latency) -> barrier(#2, drains).
// LDS 80KB -> 2 blocks/CU. Swizzles: A granule g of row r at g^((r&15)<<1);
// B slot s of row n at s^((n>>1)&3). Both verified conflict-free (R5: SQ_LDS_BANK_CONFLICT=0).
__global__ __launch_bounds__(512, 4) void k_gemm7(
    const float* __restrict__ x, int Nrows,
    const unsigned short* __restrict__ Wbf,
    const float* __restrict__ bias,
    unsigned short* __restrict__ Y,
    int j0, int j1, int j2, int j3, int nW)
{
  __shared__ unsigned short As[128*256];   // 64 KB
  __shared__ unsigned short Bs[256*32];    // 16 KB
  const int tid  = threadIdx.x;
  const int wave = tid >> 6, lane = tid & 63;
  const int l15  = lane & 15, kq = lane >> 4;
  const int wr   = wave >> 2, wc = wave & 3;
  const int rowBase = blockIdx.x * 128;

  // ---- stage A: 128 rows x 256 cols fp32 -> bf16, swizzled granules ----
  #pragma unroll
  for (int i = 0; i < 8; ++i){
    int idx = i*512 + tid;           // granule index: row = idx>>5, g = idx&31
    int r = idx >> 5, g = idx & 31;
    f32x4 v0 = {0.f,0.f,0.f,0.f}, v1 = {0.f,0.f,0.f,0.f};
    if (rowBase + r < Nrows){
      const float* p = x + (size_t)(rowBase + r)*DD + g*8;
      v0 = *(const f32x4*)p; v1 = *(const f32x4*)(p + 4);
    }
    uint32_t d[4];
    const uint32_t* a  = (const uint32_t*)&v0;
    const uint32_t* b2 = (const uint32_t*)&v1;
    d[0] = __builtin_amdgcn_perm(a[1],  a[0],  0x07060302u);
    d[1] = __builtin_amdgcn_perm(a[3],  a[2],  0x07060302u);
    d[2] = __builtin_amdgcn_perm(b2[1], b2[0], 0x07060302u);
    d[3] = __builtin_amdgcn_perm(b2[3], b2[2], 0x07060302u);
    int gs = g ^ ((r & 15) << 1);
    *(int4*)(As + r*256 + gs*8) = *(int4*)d;
  }

  const int sB = kq ^ ((l15 >> 1) & 3);    // B LDS read slot
  const int IT = nW*8;

  auto pick = [&](int jj)->int { return (jj==0) ? j0 : (jj==1) ? j1 : (jj==2) ? j2 : j3; };

  // stage B slice for flat iteration it (granule: row = idx>>2, slot = idx&3)
  auto stageB = [&](int it){
    int jj = it >> 3, ks = it & 7;
    const unsigned short* Wj = Wbf + (size_t)pick(jj)*DD*DD + ks*32;
    #pragma unroll
    for (int i = 0; i < 2; ++i){
      int idx  = i*512 + tid;
      int row  = idx >> 2;
      int slot = idx & 3;
      int srcg = slot ^ ((row >> 1) & 3);
      gload_lds16(Wj + (size_t)row*DD + srcg*8,
                  Bs + ((size_t)i*512 + wave*64)*8);
    }
  };

  stageB(0);
  __syncthreads();               // A staged + Bs(0) ready

  f32x4 acc[4][4];
  #pragma unroll
  for (int m=0;m<4;m++)
    #pragma unroll
    for (int n=0;n<4;n++)
      acc[m][n] = (f32x4){0.f,0.f,0.f,0.f};

  for (int it = 0; it < IT; ++it){
    const int jj = it >> 3, ks = it & 7;

    // phase 1: LDS -> registers (frees Bs for restaging)
    bf16x8 afr[4], bfr[4];
    #pragma unroll
    for (int m=0;m<4;m++){
      int row = wr*64 + 16*m + l15;
      int gs = (ks*4 + kq) ^ (l15 << 1);
      afr[m] = *(const bf16x8*)(As + row*256 + gs*8);
    }
    #pragma unroll
    for (int n=0;n<4;n++){
      int row = wc*64 + 16*n + l15;
      bfr[n] = *(const bf16x8*)(Bs + row*32 + sB*8);
    }
    __syncthreads();             // #1: every wave's B-reads landed; Bs reusable

    // phase 2: issue next stage; it flies under the MFMA phase
    if (it+1 < IT) stageB(it+1);

    // phase 3: pure-register MFMA
    #pragma unroll
    for (int m=0;m<4;m++)
      #pragma unroll
      for (int n=0;n<4;n++)
        acc[m][n] = __builtin_amdgcn_mfma_f32_16x16x32_bf16(afr[m], bfr[n], acc[m][n], 0,0,0);

    if (ks == 7){
      // epilogue: D row = wr*64 + 16m + 4*kq + r, col = wc*64 + 16n + l15
      const float* bj = bias + (size_t)pick(jj)*DD;
      unsigned short* Yj = Y + (size_t)jj*Nrows*DD;
      #pragma unroll
      for (int m=0;m<4;m++){
        int row0 = rowBase + wr*64 + 16*m + 4*kq;
        #pragma unroll
        for (int n=0;n<4;n++){
          int col = wc*64 + 16*n + l15;
          float bv = bj[col];
          #pragma unroll
          for (int r=0;r<4;r++){
            int row = row0 + r;
            if (row < Nrows) Yj[(size_t)row*DD + col] = f2bf(acc[m][n][r] + bv);
          }
        }
      }
      #pragma unroll
      for (int m=0;m<4;m++)
        #pragma unroll
        for (int n=0;n<4;n++)
          acc[m][n] = (f32x4){0.f,0.f,0.f,0.f};
    }

    __syncthreads();             // #2: drains stage(it+1); Bs(it+1) ready
  }
}

// ---------------- histograms ----------------
__global__ void k_hist(const int* __restrict__ ba, const int* __restrict__ b2g,
                       const int* __restrict__ a2g,
                       int* deg, int* cntb, int* cnta){
  int stride = gridDim.x*blockDim.x;
  for (int i = blockIdx.x*blockDim.x + threadIdx.x; i < NB; i += stride){
    atomicAdd(&deg[ba[2*i]],   1);
    atomicAdd(&deg[ba[2*i+1]], 1);
    atomicAdd(&cntb[b2g[i]],   1);
  }
  for (int i = blockIdx.x*blockDim.x + threadIdx.x; i < NA; i += stride)
    atomicAdd(&cnta[a2g[i]], 1);
}

// ---------------- exclusive scan (3-phase), 2048 elems/block ----------------
__global__ void k_scan_partials(const int* __restrict__ in, int n, int* __restrict__ part){
  __shared__ int sd[256];
  int base = blockIdx.x*2048;
  int s = 0;
  #pragma unroll
  for (int i=0;i<8;i++){
    int idx = base + threadIdx.x*8 + i;
    if (idx < n) s += in[idx];
  }
  sd[threadIdx.x] = s;
  __syncthreads();
  for (int off=128; off>0; off>>=1){
    if (threadIdx.x < off) sd[threadIdx.x] += sd[threadIdx.x+off];
    __syncthreads();
  }
  if (threadIdx.x==0) part[blockIdx.x] = sd[0];
}
__global__ void k_scan_small(int* part, int nb){
  if (threadIdx.x==0 && blockIdx.x==0){
    int run = 0;
    for (int i=0;i<nb;i++){ int v = part[i]; part[i] = run; run += v; }
    part[nb] = run;
  }
}
__global__ void k_scan_final(const int* __restrict__ in, int n,
                             const int* __restrict__ part, int* __restrict__ outp){
  __shared__ int sd[256];
  int base = blockIdx.x*2048;
  int loc[8];
  int s = 0;
  #pragma unroll
  for (int i=0;i<8;i++){
    int idx = base + threadIdx.x*8 + i;
    int v = (idx < n) ? in[idx] : 0;
    loc[i] = s; s += v;
  }
  sd[threadIdx.x] = s;
  __syncthreads();
  int mine = s;
  for (int off=1; off<256; off<<=1){
    int add = (threadIdx.x >= off) ? sd[threadIdx.x - off] : 0;
    __syncthreads();
    sd[threadIdx.x] += add;
    __syncthreads();
  }
  int b0 = part[blockIdx.x] + sd[threadIdx.x] - mine;
  #pragma unroll
  for (int i=0;i<8;i++){
    int idx = base + threadIdx.x*8 + i;
    if (idx < n) outp[idx] = b0 + loc[i];
  }
  if (blockIdx.x==0 && threadIdx.x==0) outp[n] = part[gridDim.x];
}

// ---------------- scatter: graph lists + bond-incidence lists ----------------
__global__ void k_scatter_atoms(const int* __restrict__ a2g, const int* __restrict__ goffa,
                                int* cura, int* alist){
  for (int i = blockIdx.x*blockDim.x + threadIdx.x; i < NA; i += gridDim.x*blockDim.x){
    int g = a2g[i];
    int p = atomicAdd(&cura[g], 1);
    alist[goffa[g] + p] = i;
  }
}
__global__ void k_scatter_bonds(const int* __restrict__ ba, const int* __restrict__ b2g,
                                const int* __restrict__ goffb, int* curb, int* blist,
                                const int* __restrict__ aoff, int* cur_atom,
                                int* incb, int* inco){
  for (int i = blockIdx.x*blockDim.x + threadIdx.x; i < NB; i += gridDim.x*blockDim.x){
    int g = b2g[i];
    int p = atomicAdd(&curb[g], 1);
    blist[goffb[g] + p] = i;
    int i0 = ba[2*i], i1 = ba[2*i+1];
    int q0 = atomicAdd(&cur_atom[i0], 1);
    incb[aoff[i0]+q0] = i; inco[aoff[i0]+q0] = i1;
    int q1 = atomicAdd(&cur_atom[i1], 1);
    incb[aoff[i1]+q1] = i; inco[aoff[i1]+q1] = i0;
  }
}

// ---------------- bond kernel: e_new, sigma, e_pre(=e_new*snorm_e), e-BN stats -----
__global__ __launch_bounds__(256) void k_bond(
    const unsigned short* __restrict__ Ah, const unsigned short* __restrict__ Be,
    const unsigned short* __restrict__ Cu,
    const int* __restrict__ ba, const int* __restrict__ b2g,
    const float* __restrict__ sne,
    unsigned short* __restrict__ Sg, float* __restrict__ e_pre,
    float* esum, float* esumsq)
{
  const int wave = threadIdx.x >> 6, lane = threadIdx.x & 63;
  float s1[4] = {0,0,0,0}, s2[4] = {0,0,0,0};
  const int wstride = gridDim.x*4;
  for (int bond = blockIdx.x*4 + wave; bond < NB; bond += wstride){
    int i0 = ba[2*bond], i1 = ba[2*bond+1];
    int g  = b2g[bond];
    float sn = sne[bond];
    ushort4 a0 = *(const ushort4*)(Ah + (size_t)i0*DD + lane*4);
    ushort4 a1 = *(const ushort4*)(Ah + (size_t)i1*DD + lane*4);
    ushort4 be = *(const ushort4*)(Be + (size_t)bond*DD + lane*4);
    ushort4 cu = *(const ushort4*)(Cu + (size_t)g*DD + lane*4);
    float e0 = bf2f(a0.x)+bf2f(a1.x)+bf2f(be.x)+bf2f(cu.x);
    float e1 = bf2f(a0.y)+bf2f(a1.y)+bf2f(be.y)+bf2f(cu.y);
    float e2 = bf2f(a0.z)+bf2f(a1.z)+bf2f(be.z)+bf2f(cu.z);
    float e3 = bf2f(a0.w)+bf2f(a1.w)+bf2f(be.w)+bf2f(cu.w);
    ushort4 sg;
    sg.x = f2bf(1.f/(1.f+__expf(-e0)));
    sg.y = f2bf(1.f/(1.f+__expf(-e1)));
    sg.z = f2bf(1.f/(1.f+__expf(-e2)));
    sg.w = f2bf(1.f/(1.f+__expf(-e3)));
    *(ushort4*)(Sg + (size_t)bond*DD + lane*4) = sg;
    float4 ep; ep.x = e0*sn; ep.y = e1*sn; ep.z = e2*sn; ep.w = e3*sn;
    *(float4*)(e_pre + (size_t)bond*DD + lane*4) = ep;
    s1[0]+=ep.x; s2[0]+=ep.x*ep.x;
    s1[1]+=ep.y; s2[1]+=ep.y*ep.y;
    s1[2]+=ep.z; s2[2]+=ep.z*ep.z;
    s1[3]+=ep.w; s2[3]+=ep.w*ep.w;
  }
  __shared__ float red[4*DD];
  #pragma unroll
  for (int c=0;c<4;c++) red[wave*DD + lane*4 + c] = s1[c];
  __syncthreads();
  if (threadIdx.x < DD){
    float t = red[threadIdx.x] + red[DD+threadIdx.x] + red[2*DD+threadIdx.x] + red[3*DD+threadIdx.x];
    atomicAdd(&esum[threadIdx.x], t);
  }
  __syncthreads();
  #pragma unroll
  for (int c=0;c<4;c++) red[wave*DD + lane*4 + c] = s2[c];
  __syncthreads();
  if (threadIdx.x < DD){
    float t = red[threadIdx.x] + red[DD+threadIdx.x] + red[2*DD+threadIdx.x] + red[3*DD+threadIdx.x];
    atomicAdd(&esumsq[threadIdx.x], t);
  }
}

// ---------------- atom kernel: gate via incidence CSR, h_pre, h-BN stats -----------
__global__ __launch_bounds__(256) void k_atom(
    const unsigned short* __restrict__ Dh, const unsigned short* __restrict__ Eh,
    const unsigned short* __restrict__ Fu, const unsigned short* __restrict__ Sg,
    const int* __restrict__ aoff, const int* __restrict__ incb, const int* __restrict__ inco,
    const int* __restrict__ a2g, const float* __restrict__ snn,
    float* __restrict__ h_pre, float* hsum, float* hsumsq)
{
  const int wave = threadIdx.x >> 6, lane = threadIdx.x & 63;
  float s1[4] = {0,0,0,0}, s2[4] = {0,0,0,0};
  const int wstride = gridDim.x*4;
  for (int a = blockIdx.x*4 + wave; a < NA; a += wstride){
    int j0 = aoff[a], j1 = aoff[a+1];
    float num[4] = {0,0,0,0}, den[4] = {0,0,0,0};
    for (int j = j0; j < j1; ++j){
      int bond = incb[j], other = inco[j];
      ushort4 sg = *(const ushort4*)(Sg + (size_t)bond*DD + lane*4);
      ushort4 eo = *(const ushort4*)(Eh + (size_t)other*DD + lane*4);
      float g0 = bf2f(sg.x), g1 = bf2f(sg.y), g2 = bf2f(sg.z), g3 = bf2f(sg.w);
      num[0] += g0*bf2f(eo.x); num[1] += g1*bf2f(eo.y);
      num[2] += g2*bf2f(eo.z); num[3] += g3*bf2f(eo.w);
      den[0] += g0; den[1] += g1; den[2] += g2; den[3] += g3;
    }
    int g = a2g[a]; float sn = snn[a];
    ushort4 dh = *(const ushort4*)(Dh + (size_t)a*DD + lane*4);
    ushort4 fu = *(const ushort4*)(Fu + (size_t)g*DD + lane*4);
    float4 hv;
    hv.x = (bf2f(dh.x) + num[0]/(den[0]+EPS_GATE) + bf2f(fu.x))*sn;
    hv.y = (bf2f(dh.y) + num[1]/(den[1]+EPS_GATE) + bf2f(fu.y))*sn;
    hv.z = (bf2f(dh.z) + num[2]/(den[2]+EPS_GATE) + bf2f(fu.z))*sn;
    hv.w = (bf2f(dh.w) + num[3]/(den[3]+EPS_GATE) + bf2f(fu.w))*sn;
    *(float4*)(h_pre + (size_t)a*DD + lane*4) = hv;
    s1[0]+=hv.x; s2[0]+=hv.x*hv.x;
    s1[1]+=hv.y; s2[1]+=hv.y*hv.y;
    s1[2]+=hv.z; s2[2]+=hv.z*hv.z;
    s1[3]+=hv.w; s2[3]+=hv.w*hv.w;
  }
  __shared__ float red[4*DD];
  #pragma unroll
  for (int c=0;c<4;c++) red[wave*DD + lane*4 + c] = s1[c];
  __syncthreads();
  if (threadIdx.x < DD){
    float t = red[threadIdx.x] + red[DD+threadIdx.x] + red[2*DD+threadIdx.x] + red[3*DD+threadIdx.x];
    atomicAdd(&hsum[threadIdx.x], t);
  }
  __syncthreads();
  #pragma unroll
  for (int c=0;c<4;c++) red[wave*DD + lane*4 + c] = s2[c];
  __syncthreads();
  if (threadIdx.x < DD){
    float t = red[threadIdx.x] + red[DD+threadIdx.x] + red[2*DD+threadIdx.x] + red[3*DD+threadIdx.x];
    atomicAdd(&hsumsq[threadIdx.x], t);
  }
}

// ---------------- graph kernel: u_pre per graph (block per graph) ------------------
__global__ __launch_bounds__(256) void k_graph(
    const unsigned short* __restrict__ Gh, const unsigned short* __restrict__ He,
    const unsigned short* __restrict__ Iu,
    const int* __restrict__ goffa, const int* __restrict__ alist,
    const int* __restrict__ goffb, const int* __restrict__ blist,
    float* __restrict__ u_pre)
{
  int g = blockIdx.x, t = threadIdx.x;
  int a0 = goffa[g], a1 = goffa[g+1];
  float sA = 0.f;
  for (int i = a0; i < a1; ++i) sA += bf2f(Gh[(size_t)alist[i]*DD + t]);
  int b0 = goffb[g], b1 = goffb[g+1];
  float sB = 0.f;
  for (int i = b0; i < b1; ++i) sB += bf2f(He[(size_t)blist[i]*DD + t]);
  float cA = (float)max(a1 - a0, 1);
  float cB = (float)max(b1 - b0, 1);
  u_pre[(size_t)g*DD + t] = sA/cA + sB/cB + bf2f(Iu[(size_t)g*DD + t]);
}

__global__ void k_ustats(const float* __restrict__ u_pre, float* usum, float* usumsq){
  int t = threadIdx.x;
  float s = 0.f, s2 = 0.f;
  for (int g = blockIdx.x; g < NG; g += gridDim.x){
    float v = u_pre[(size_t)g*DD + t];
    s += v; s2 += v*v;
  }
  atomicAdd(&usum[t], s);
  atomicAdd(&usumsq[t], s2);
}

// ---------------- BN finalize + normalize/ELU ----------------
__global__ void k_bnfin(const float* __restrict__ sums, const float* __restrict__ sumsq,
                        float* __restrict__ mr){
  int o = blockIdx.x, t = threadIdx.x;
  float n = (o==0) ? (float)NA : (o==1) ? (float)NB : (float)NG;
  float m = sums[o*DD+t]/n;
  float v = sumsq[o*DD+t]/n - m*m;
  mr[o*2*DD + t]      = m;
  mr[o*2*DD + DD + t] = rsqrtf(fmaxf(v, 0.f) + EPS_BN);
}

__global__ __launch_bounds__(256) void k_norm(
    float* __restrict__ buf, size_t nrows,
    const float* __restrict__ mr, const float* __restrict__ gamma,
    const float* __restrict__ beta)
{
  __shared__ float sm[DD], sr[DD], sg[DD], sb[DD];
  int t = threadIdx.x;
  sm[t] = mr[t]; sr[t] = mr[DD+t]; sg[t] = gamma[t]; sb[t] = beta[t];
  __syncthreads();
  size_t total = nrows*(DD/4);
  for (size_t i = blockIdx.x*(size_t)blockDim.x + t; i < total;
       i += (size_t)gridDim.x*blockDim.x){
    int c = ((int)(i & 63))*4;
    float4 v = ((float4*)buf)[i];
    float z0 = (v.x - sm[c+0])*sr[c+0]*sg[c+0] + sb[c+0];
    float z1 = (v.y - sm[c+1])*sr[c+1]*sg[c+1] + sb[c+1];
    float z2 = (v.z - sm[c+2])*sr[c+2]*sg[c+2] + sb[c+2];
    float z3 = (v.w - sm[c+3])*sr[c+3]*sg[c+3] + sb[c+3];
    v.x = z0 > 0.f ? z0 : expm1f(z0);
    v.y = z1 > 0.f ? z1 : expm1f(z1);
    v.z = z2 > 0.f ? z2 : expm1f(z2);
    v.w = z3 > 0.f ? z3 : expm1f(z3);
    ((float4*)buf)[i] = v;
  }
}

// ================================ launcher =================================
extern "C" void kernel_launch(void* const* d_in, const int* in_sizes, int n_in,
                              void* d_out, int out_size, void* d_ws, size_t ws_size,
                              hipStream_t stream)
{
  (void)in_sizes; (void)n_in; (void)out_size;
  const float* h   = (const float*)d_in[0];
  const float* e   = (const float*)d_in[1];
  const float* u   = (const float*)d_in[2];
  const float* snn = (const float*)d_in[3];
  const float* sne = (const float*)d_in[4];
  const float* W   = (const float*)d_in[5];
  const float* b   = (const float*)d_in[6];
  const float* gamma = (const float*)d_in[7];
  const float* beta  = (const float*)d_in[8];
  const int* ba  = (const int*)d_in[9];
  const int* a2g = (const int*)d_in[10];
  const int* b2g = (const int*)d_in[11];

  float* outp  = (float*)d_out;
  float* h_pre = outp;
  float* e_pre = outp + (size_t)NA*DD;
  float* u_pre = outp + (size_t)(NA+NB)*DD;

  char* ws = (char*)d_ws;
  size_t off = 0;
  auto alloc = [&](size_t bytes)->char* {
    char* p = ws + off;
    off += (bytes + 255) & ~(size_t)255;
    return p;
  };
  unsigned short* Wbf = (unsigned short*)alloc((size_t)9*DD*DD*2);
  unsigned short* Yh  = (unsigned short*)alloc((size_t)4*NA*DD*2);
  unsigned short* Ye  = (unsigned short*)alloc((size_t)2*NB*DD*2);
  unsigned short* Yu  = (unsigned short*)alloc((size_t)3*NG*DD*2);
  unsigned short* Sg  = (unsigned short*)alloc((size_t)NB*DD*2);
  int* aoff  = (int*)alloc((size_t)(NA+1)*4);
  int* goffa = (int*)alloc((size_t)(NG+1)*4);
  int* goffb = (int*)alloc((size_t)(NG+1)*4);
  int* alist = (int*)alloc((size_t)NA*4);
  int* blist = (int*)alloc((size_t)NB*4);
  int* incb  = (int*)alloc((size_t)2*NB*4);
  int* inco  = (int*)alloc((size_t)2*NB*4);
  int* part  = (int*)alloc(1024);
  float* mr  = (float*)alloc((size_t)3*2*DD*4);
  char* zz   = ws + off;                      // ---- zero zone start ----
  int* deg      = (int*)alloc((size_t)NA*4);
  int* cur_atom = (int*)alloc((size_t)NA*4);
  int* cnta  = (int*)alloc((size_t)NG*4);
  int* cntb  = (int*)alloc((size_t)NG*4);
  int* cura  = (int*)alloc((size_t)NG*4);
  int* curb  = (int*)alloc((size_t)NG*4);
  float* sums  = (float*)alloc((size_t)3*DD*4);
  float* sumsq = (float*)alloc((size_t)3*DD*4);
  size_t zbytes = (size_t)((ws + off) - zz);

  if (ws_size < off) return;

  unsigned short* Ah = Yh;
  unsigned short* Dh = Yh + (size_t)1*NA*DD;
  unsigned short* Eh = Yh + (size_t)2*NA*DD;
  unsigned short* Gh = Yh + (size_t)3*NA*DD;
  unsigned short* Be = Ye;
  unsigned short* He = Ye + (size_t)NB*DD;
  unsigned short* Cu = Yu;
  unsigned short* Fu = Yu + (size_t)1*NG*DD;
  unsigned short* Iu = Yu + (size_t)2*NG*DD;

  k_zero<<<256, 256, 0, stream>>>((int4*)zz, zbytes/16);
  k_wconv<<<288, 256, 0, stream>>>(W, Wbf, 9*DD*DD/4);

  k_gemm7<<<(NA+127)/128, 512, 0, stream>>>(h, NA, Wbf, b, Yh, 0,3,4,6, 4);
  k_gemm7<<<(NB+127)/128, 512, 0, stream>>>(e, NB, Wbf, b, Ye, 1,7,0,0, 2);
  k_gemm7<<<(NG+127)/128, 512, 0, stream>>>(u, NG, Wbf, b, Yu, 2,5,8,0, 3);

  k_hist<<<1024, 256, 0, stream>>>(ba, b2g, a2g, deg, cntb, cnta);

  k_scan_partials<<<98, 256, 0, stream>>>(deg, NA, part);
  k_scan_small<<<1, 64, 0, stream>>>(part, 98);
  k_scan_final<<<98, 256, 0, stream>>>(deg, NA, part, aoff);
  k_scan_partials<<<5, 256, 0, stream>>>(cnta, NG, part);
  k_scan_small<<<1, 64, 0, stream>>>(part, 5);
  k_scan_final<<<5, 256, 0, stream>>>(cnta, NG, part, goffa);
  k_scan_partials<<<5, 256, 0, stream>>>(cntb, NG, part);
  k_scan_small<<<1, 64, 0, stream>>>(part, 5);
  k_scan_final<<<5, 256, 0, stream>>>(cntb, NG, part, goffb);

  k_scatter_atoms<<<512, 256, 0, stream>>>(a2g, goffa, cura, alist);
  k_scatter_bonds<<<512, 256, 0, stream>>>(ba, b2g, goffb, curb, blist,
                                           aoff, cur_atom, incb, inco);

  k_bond<<<2048, 256, 0, stream>>>(Ah, Be, Cu, ba, b2g, sne, Sg, e_pre,
                                   sums + DD, sumsq + DD);
  k_atom<<<2048, 256, 0, stream>>>(Dh, Eh, Fu, Sg, aoff, incb, inco, a2g, snn,
                                   h_pre, sums + 0, sumsq + 0);
  k_graph<<<NG, 256, 0, stream>>>(Gh, He, Iu, goffa, alist, goffb, blist, u_pre);
  k_ustats<<<40, 256, 0, stream>>>(u_pre, sums + 2*DD, sumsq + 2*DD);

  k_bnfin<<<3, 256, 0, stream>>>(sums, sumsq, mr);

  k_norm<<<2048, 256, 0, stream>>>(h_pre, (size_t)NA, mr + 0,      gamma + 0,    beta + 0);
  k_norm<<<2048, 256, 0, stream>>>(e_pre, (size_t)NB, mr + 2*DD,   gamma + DD,   beta + DD);
  k_norm<<<64,   256, 0, stream>>>(u_pre, (size_t)NG, mr + 4*DD,   gamma + 2*DD, beta + 2*DD);
}

// Round 9
// 1539.381 us; speedup vs baseline: 1.3531x; 1.3531x over previous
//
#include <hip/hip_runtime.h>
#include <stdint.h>

#define NA 200000
#define NB 300000
#define NG 10000
#define DD 256
#define EPS_GATE 1e-6f
#define EPS_BN 1e-5f

typedef short bf16x8 __attribute__((ext_vector_type(8)));
typedef float f32x4 __attribute__((ext_vector_type(4)));

__device__ __forceinline__ unsigned short f2bf(float f){
  union { float f; uint32_t u; } v; v.f = f;
  uint32_t uu = v.u;
  uint32_t r = (uu + 0x7FFFu + ((uu >> 16) & 1u)) >> 16;
  return (unsigned short)r;
}
__device__ __forceinline__ float bf2f(unsigned short s){
  union { uint32_t u; float f; } v; v.u = ((uint32_t)s) << 16; return v.f;
}

__device__ __forceinline__ void gload_lds16(const unsigned short* g, unsigned short* l){
  __builtin_amdgcn_global_load_lds(
      (const __attribute__((address_space(1))) unsigned int*)g,
      (__attribute__((address_space(3))) unsigned int*)l, 16, 0, 0);
}

// ---------------- zero fill ----------------
__global__ void k_zero(int4* p, size_t n16){
  for (size_t i = blockIdx.x*(size_t)blockDim.x + threadIdx.x; i < n16;
       i += (size_t)gridDim.x*blockDim.x)
    p[i] = make_int4(0,0,0,0);
}

// ---------------- W fp32 -> bf16 ----------------
__global__ void k_wconv(const float* __restrict__ W, unsigned short* __restrict__ Wbf, int n4){
  for (int i = blockIdx.x*blockDim.x + threadIdx.x; i < n4; i += gridDim.x*blockDim.x){
    float4 v = ((const float4*)W)[i];
    ushort4 o; o.x = f2bf(v.x); o.y = f2bf(v.y); o.z = f2bf(v.z); o.w = f2bf(v.w);
    ((ushort4*)Wbf)[i] = o;
  }
}

// ====== T3+T4 fused GEMM: dbuf B + counted vmcnt + raw barriers ======
// 512 thr (8 waves: wr in {0,1}, wc in {0..3}). Tile 96 rows x 256 cols.
// A (96x256 full-K) swizzled bf16 in LDS (48KB), staged once.
// B: 256x32 slice DOUBLE-buffered (2x16KB). Per K-step:
//   issue stage(ks+1 -> other buf) -> s_waitcnt vmcnt(2) (stage(ks) landed;
//   stage(ks+1) stays in flight ACROSS the barrier) -> s_barrier ->
//   ds_read frags -> 12 MFMA -> s_barrier.
// ks==7 uses vmcnt(0) so epilogue stores fly with NO loads in flight (R8 lesson).
// LDS 80KB -> 2 blocks/CU (same occupancy as R5 champion).
// Swizzles (verified conflict-free, R5): A granule g of row r at g^((r&15)<<1);
// B slot s of row n at s^((n>>1)&3).
__global__ __launch_bounds__(512, 4) void k_gemm8(
    const float* __restrict__ x, int Nrows,
    const unsigned short* __restrict__ Wbf,
    const float* __restrict__ bias,
    unsigned short* __restrict__ Y,
    int j0, int j1, int j2, int j3, int nW)
{
  __shared__ unsigned short As[96*256];     // 48 KB
  __shared__ unsigned short Bs[2*256*32];   // 32 KB
  const int tid  = threadIdx.x;
  const int wave = tid >> 6, lane = tid & 63;
  const int l15  = lane & 15, kq = lane >> 4;
  const int wr   = wave >> 2, wc = wave & 3;
  const int rowBase = blockIdx.x * 96;

  // ---- stage A: 96 rows x 256 cols fp32 -> bf16, swizzled granules ----
  #pragma unroll
  for (int i = 0; i < 6; ++i){
    int idx = i*512 + tid;           // granule index: row = idx>>5, g = idx&31
    int r = idx >> 5, g = idx & 31;
    f32x4 v0 = {0.f,0.f,0.f,0.f}, v1 = {0.f,0.f,0.f,0.f};
    if (rowBase + r < Nrows){
      const float* p = x + (size_t)(rowBase + r)*DD + g*8;
      v0 = *(const f32x4*)p; v1 = *(const f32x4*)(p + 4);
    }
    uint32_t d[4];
    const uint32_t* a  = (const uint32_t*)&v0;
    const uint32_t* b2 = (const uint32_t*)&v1;
    d[0] = __builtin_amdgcn_perm(a[1],  a[0],  0x07060302u);
    d[1] = __builtin_amdgcn_perm(a[3],  a[2],  0x07060302u);
    d[2] = __builtin_amdgcn_perm(b2[1], b2[0], 0x07060302u);
    d[3] = __builtin_amdgcn_perm(b2[3], b2[2], 0x07060302u);
    int gs = g ^ ((r & 15) << 1);
    *(int4*)(As + r*256 + gs*8) = *(int4*)d;
  }

  const int sB = kq ^ ((l15 >> 1) & 3);    // B LDS read slot

  auto pick = [&](int jj)->int { return (jj==0) ? j0 : (jj==1) ? j1 : (jj==2) ? j2 : j3; };

  // stage B slice ks of weight j into buffer buf (granule: row = idx>>2, slot = idx&3)
  auto stageB = [&](int j, int ks, int buf){
    const unsigned short* Wj = Wbf + (size_t)j*DD*DD + ks*32;
    unsigned short* dst = Bs + (size_t)buf*(256*32);
    #pragma unroll
    for (int i = 0; i < 2; ++i){
      int idx  = i*512 + tid;
      int row  = idx >> 2;
      int slot = idx & 3;
      int srcg = slot ^ ((row >> 1) & 3);
      gload_lds16(Wj + (size_t)row*DD + srcg*8,
                  dst + ((size_t)i*512 + wave*64)*8);
    }
  };

  stageB(pick(0), 0, 0);
  __syncthreads();               // A staged (drains everything) + Bs[0] ready

  for (int jj = 0; jj < nW; ++jj){
    const int j = pick(jj);
    f32x4 acc[3][4];
    #pragma unroll
    for (int m=0;m<3;m++)
      #pragma unroll
      for (int n=0;n<4;n++)
        acc[m][n] = (f32x4){0.f,0.f,0.f,0.f};

    #pragma unroll
    for (int ks = 0; ks < 8; ++ks){
      if (ks < 7){
        stageB(j, ks+1, (ks+1)&1);                       // into the OTHER buffer
        asm volatile("s_waitcnt vmcnt(2)" ::: "memory"); // stage(ks) landed; ks+1 in flight
      } else {
        asm volatile("s_waitcnt vmcnt(0)" ::: "memory"); // drain before epilogue stores
      }
      __builtin_amdgcn_s_barrier();                      // b[ks&1] ready for all waves

      const unsigned short* Bb = Bs + (size_t)(ks&1)*(256*32);
      bf16x8 afr[3], bfr[4];
      #pragma unroll
      for (int m=0;m<3;m++){
        int row = wr*48 + 16*m + l15;
        int gs = (ks*4 + kq) ^ (l15 << 1);
        afr[m] = *(const bf16x8*)(As + row*256 + gs*8);
      }
      #pragma unroll
      for (int n=0;n<4;n++){
        int row = wc*64 + 16*n + l15;
        bfr[n] = *(const bf16x8*)(Bb + row*32 + sB*8);
      }
      #pragma unroll
      for (int m=0;m<3;m++)
        #pragma unroll
        for (int n=0;n<4;n++)
          acc[m][n] = __builtin_amdgcn_mfma_f32_16x16x32_bf16(afr[m], bfr[n], acc[m][n], 0,0,0);

      __builtin_amdgcn_s_barrier();                      // all waves done reading b[ks&1]
    }

    // epilogue (no loads in flight): D row = wr*48 + 16m + 4*kq + r, col = wc*64 + 16n + l15
    const float* bj = bias + (size_t)j*DD;
    unsigned short* Yj = Y + (size_t)jj*Nrows*DD;
    #pragma unroll
    for (int m=0;m<3;m++){
      int row0 = rowBase + wr*48 + 16*m + 4*kq;
      #pragma unroll
      for (int n=0;n<4;n++){
        int col = wc*64 + 16*n + l15;
        float bv = bj[col];
        #pragma unroll
        for (int r=0;r<4;r++){
          int row = row0 + r;
          if (row < Nrows) Yj[(size_t)row*DD + col] = f2bf(acc[m][n][r] + bv);
        }
      }
    }

    if (jj+1 < nW) stageB(pick(jj+1), 0, 0);   // prefetch next weight's slice 0
  }
}

// ---------------- histograms ----------------
__global__ void k_hist(const int* __restrict__ ba, const int* __restrict__ b2g,
                       const int* __restrict__ a2g,
                       int* deg, int* cntb, int* cnta){
  int stride = gridDim.x*blockDim.x;
  for (int i = blockIdx.x*blockDim.x + threadIdx.x; i < NB; i += stride){
    atomicAdd(&deg[ba[2*i]],   1);
    atomicAdd(&deg[ba[2*i+1]], 1);
    atomicAdd(&cntb[b2g[i]],   1);
  }
  for (int i = blockIdx.x*blockDim.x + threadIdx.x; i < NA; i += stride)
    atomicAdd(&cnta[a2g[i]], 1);
}

// ---------------- exclusive scan (3-phase), 2048 elems/block ----------------
__global__ void k_scan_partials(const int* __restrict__ in, int n, int* __restrict__ part){
  __shared__ int sd[256];
  int base = blockIdx.x*2048;
  int s = 0;
  #pragma unroll
  for (int i=0;i<8;i++){
    int idx = base + threadIdx.x*8 + i;
    if (idx < n) s += in[idx];
  }
  sd[threadIdx.x] = s;
  __syncthreads();
  for (int off=128; off>0; off>>=1){
    if (threadIdx.x < off) sd[threadIdx.x] += sd[threadIdx.x+off];
    __syncthreads();
  }
  if (threadIdx.x==0) part[blockIdx.x] = sd[0];
}
__global__ void k_scan_small(int* part, int nb){
  if (threadIdx.x==0 && blockIdx.x==0){
    int run = 0;
    for (int i=0;i<nb;i++){ int v = part[i]; part[i] = run; run += v; }
    part[nb] = run;
  }
}
__global__ void k_scan_final(const int* __restrict__ in, int n,
                             const int* __restrict__ part, int* __restrict__ outp){
  __shared__ int sd[256];
  int base = blockIdx.x*2048;
  int loc[8];
  int s = 0;
  #pragma unroll
  for (int i=0;i<8;i++){
    int idx = base + threadIdx.x*8 + i;
    int v = (idx < n) ? in[idx] : 0;
    loc[i] = s; s += v;
  }
  sd[threadIdx.x] = s;
  __syncthreads();
  int mine = s;
  for (int off=1; off<256; off<<=1){
    int add = (threadIdx.x >= off) ? sd[threadIdx.x - off] : 0;
    __syncthreads();
    sd[threadIdx.x] += add;
    __syncthreads();
  }
  int b0 = part[blockIdx.x] + sd[threadIdx.x] - mine;
  #pragma unroll
  for (int i=0;i<8;i++){
    int idx = base + threadIdx.x*8 + i;
    if (idx < n) outp[idx] = b0 + loc[i];
  }
  if (blockIdx.x==0 && threadIdx.x==0) outp[n] = part[gridDim.x];
}

// ---------------- scatter: graph lists + bond-incidence lists ----------------
__global__ void k_scatter_atoms(const int* __restrict__ a2g, const int* __restrict__ goffa,
                                int* cura, int* alist){
  for (int i = blockIdx.x*blockDim.x + threadIdx.x; i < NA; i += gridDim.x*blockDim.x){
    int g = a2g[i];
    int p = atomicAdd(&cura[g], 1);
    alist[goffa[g] + p] = i;
  }
}
__global__ void k_scatter_bonds(const int* __restrict__ ba, const int* __restrict__ b2g,
                                const int* __restrict__ goffb, int* curb, int* blist,
                                const int* __restrict__ aoff, int* cur_atom,
                                int* incb, int* inco){
  for (int i = blockIdx.x*blockDim.x + threadIdx.x; i < NB; i += gridDim.x*blockDim.x){
    int g = b2g[i];
    int p = atomicAdd(&curb[g], 1);
    blist[goffb[g] + p] = i;
    int i0 = ba[2*i], i1 = ba[2*i+1];
    int q0 = atomicAdd(&cur_atom[i0], 1);
    incb[aoff[i0]+q0] = i; inco[aoff[i0]+q0] = i1;
    int q1 = atomicAdd(&cur_atom[i1], 1);
    incb[aoff[i1]+q1] = i; inco[aoff[i1]+q1] = i0;
  }
}

// ---------------- bond kernel: e_new, sigma, e_pre(=e_new*snorm_e), e-BN stats -----
__global__ __launch_bounds__(256) void k_bond(
    const unsigned short* __restrict__ Ah, const unsigned short* __restrict__ Be,
    const unsigned short* __restrict__ Cu,
    const int* __restrict__ ba, const int* __restrict__ b2g,
    const float* __restrict__ sne,
    unsigned short* __restrict__ Sg, float* __restrict__ e_pre,
    float* esum, float* esumsq)
{
  const int wave = threadIdx.x >> 6, lane = threadIdx.x & 63;
  float s1[4] = {0,0,0,0}, s2[4] = {0,0,0,0};
  const int wstride = gridDim.x*4;
  for (int bond = blockIdx.x*4 + wave; bond < NB; bond += wstride){
    int i0 = ba[2*bond], i1 = ba[2*bond+1];
    int g  = b2g[bond];
    float sn = sne[bond];
    ushort4 a0 = *(const ushort4*)(Ah + (size_t)i0*DD + lane*4);
    ushort4 a1 = *(const ushort4*)(Ah + (size_t)i1*DD + lane*4);
    ushort4 be = *(const ushort4*)(Be + (size_t)bond*DD + lane*4);
    ushort4 cu = *(const ushort4*)(Cu + (size_t)g*DD + lane*4);
    float e0 = bf2f(a0.x)+bf2f(a1.x)+bf2f(be.x)+bf2f(cu.x);
    float e1 = bf2f(a0.y)+bf2f(a1.y)+bf2f(be.y)+bf2f(cu.y);
    float e2 = bf2f(a0.z)+bf2f(a1.z)+bf2f(be.z)+bf2f(cu.z);
    float e3 = bf2f(a0.w)+bf2f(a1.w)+bf2f(be.w)+bf2f(cu.w);
    ushort4 sg;
    sg.x = f2bf(1.f/(1.f+__expf(-e0)));
    sg.y = f2bf(1.f/(1.f+__expf(-e1)));
    sg.z = f2bf(1.f/(1.f+__expf(-e2)));
    sg.w = f2bf(1.f/(1.f+__expf(-e3)));
    *(ushort4*)(Sg + (size_t)bond*DD + lane*4) = sg;
    float4 ep; ep.x = e0*sn; ep.y = e1*sn; ep.z = e2*sn; ep.w = e3*sn;
    *(float4*)(e_pre + (size_t)bond*DD + lane*4) = ep;
    s1[0]+=ep.x; s2[0]+=ep.x*ep.x;
    s1[1]+=ep.y; s2[1]+=ep.y*ep.y;
    s1[2]+=ep.z; s2[2]+=ep.z*ep.z;
    s1[3]+=ep.w; s2[3]+=ep.w*ep.w;
  }
  __shared__ float red[4*DD];
  #pragma unroll
  for (int c=0;c<4;c++) red[wave*DD + lane*4 + c] = s1[c];
  __syncthreads();
  if (threadIdx.x < DD){
    float t = red[threadIdx.x] + red[DD+threadIdx.x] + red[2*DD+threadIdx.x] + red[3*DD+threadIdx.x];
    atomicAdd(&esum[threadIdx.x], t);
  }
  __syncthreads();
  #pragma unroll
  for (int c=0;c<4;c++) red[wave*DD + lane*4 + c] = s2[c];
  __syncthreads();
  if (threadIdx.x < DD){
    float t = red[threadIdx.x] + red[DD+threadIdx.x] + red[2*DD+threadIdx.x] + red[3*DD+threadIdx.x];
    atomicAdd(&esumsq[threadIdx.x], t);
  }
}

// ---------------- atom kernel: gate via incidence CSR, h_pre, h-BN stats -----------
__global__ __launch_bounds__(256) void k_atom(
    const unsigned short* __restrict__ Dh, const unsigned short* __restrict__ Eh,
    const unsigned short* __restrict__ Fu, const unsigned short* __restrict__ Sg,
    const int* __restrict__ aoff, const int* __restrict__ incb, const int* __restrict__ inco,
    const int* __restrict__ a2g, const float* __restrict__ snn,
    float* __restrict__ h_pre, float* hsum, float* hsumsq)
{
  const int wave = threadIdx.x >> 6, lane = threadIdx.x & 63;
  float s1[4] = {0,0,0,0}, s2[4] = {0,0,0,0};
  const int wstride = gridDim.x*4;
  for (int a = blockIdx.x*4 + wave; a < NA; a += wstride){
    int j0 = aoff[a], j1 = aoff[a+1];
    float num[4] = {0,0,0,0}, den[4] = {0,0,0,0};
    for (int j = j0; j < j1; ++j){
      int bond = incb[j], other = inco[j];
      ushort4 sg = *(const ushort4*)(Sg + (size_t)bond*DD + lane*4);
      ushort4 eo = *(const ushort4*)(Eh + (size_t)other*DD + lane*4);
      float g0 = bf2f(sg.x), g1 = bf2f(sg.y), g2 = bf2f(sg.z), g3 = bf2f(sg.w);
      num[0] += g0*bf2f(eo.x); num[1] += g1*bf2f(eo.y);
      num[2] += g2*bf2f(eo.z); num[3] += g3*bf2f(eo.w);
      den[0] += g0; den[1] += g1; den[2] += g2; den[3] += g3;
    }
    int g = a2g[a]; float sn = snn[a];
    ushort4 dh = *(const ushort4*)(Dh + (size_t)a*DD + lane*4);
    ushort4 fu = *(const ushort4*)(Fu + (size_t)g*DD + lane*4);
    float4 hv;
    hv.x = (bf2f(dh.x) + num[0]/(den[0]+EPS_GATE) + bf2f(fu.x))*sn;
    hv.y = (bf2f(dh.y) + num[1]/(den[1]+EPS_GATE) + bf2f(fu.y))*sn;
    hv.z = (bf2f(dh.z) + num[2]/(den[2]+EPS_GATE) + bf2f(fu.z))*sn;
    hv.w = (bf2f(dh.w) + num[3]/(den[3]+EPS_GATE) + bf2f(fu.w))*sn;
    *(float4*)(h_pre + (size_t)a*DD + lane*4) = hv;
    s1[0]+=hv.x; s2[0]+=hv.x*hv.x;
    s1[1]+=hv.y; s2[1]+=hv.y*hv.y;
    s1[2]+=hv.z; s2[2]+=hv.z*hv.z;
    s1[3]+=hv.w; s2[3]+=hv.w*hv.w;
  }
  __shared__ float red[4*DD];
  #pragma unroll
  for (int c=0;c<4;c++) red[wave*DD + lane*4 + c] = s1[c];
  __syncthreads();
  if (threadIdx.x < DD){
    float t = red[threadIdx.x] + red[DD+threadIdx.x] + red[2*DD+threadIdx.x] + red[3*DD+threadIdx.x];
    atomicAdd(&hsum[threadIdx.x], t);
  }
  __syncthreads();
  #pragma unroll
  for (int c=0;c<4;c++) red[wave*DD + lane*4 + c] = s2[c];
  __syncthreads();
  if (threadIdx.x < DD){
    float t = red[threadIdx.x] + red[DD+threadIdx.x] + red[2*DD+threadIdx.x] + red[3*DD+threadIdx.x];
    atomicAdd(&hsumsq[threadIdx.x], t);
  }
}

// ---------------- graph kernel: u_pre per graph (block per graph) ------------------
__global__ __launch_bounds__(256) void k_graph(
    const unsigned short* __restrict__ Gh, const unsigned short* __restrict__ He,
    const unsigned short* __restrict__ Iu,
    const int* __restrict__ goffa, const int* __restrict__ alist,
    const int* __restrict__ goffb, const int* __restrict__ blist,
    float* __restrict__ u_pre)
{
  int g = blockIdx.x, t = threadIdx.x;
  int a0 = goffa[g], a1 = goffa[g+1];
  float sA = 0.f;
  for (int i = a0; i < a1; ++i) sA += bf2f(Gh[(size_t)alist[i]*DD + t]);
  int b0 = goffb[g], b1 = goffb[g+1];
  float sB = 0.f;
  for (int i = b0; i < b1; ++i) sB += bf2f(He[(size_t)blist[i]*DD + t]);
  float cA = (float)max(a1 - a0, 1);
  float cB = (float)max(b1 - b0, 1);
  u_pre[(size_t)g*DD + t] = sA/cA + sB/cB + bf2f(Iu[(size_t)g*DD + t]);
}

__global__ void k_ustats(const float* __restrict__ u_pre, float* usum, float* usumsq){
  int t = threadIdx.x;
  float s = 0.f, s2 = 0.f;
  for (int g = blockIdx.x; g < NG; g += gridDim.x){
    float v = u_pre[(size_t)g*DD + t];
    s += v; s2 += v*v;
  }
  atomicAdd(&usum[t], s);
  atomicAdd(&usumsq[t], s2);
}

// ---------------- BN finalize + normalize/ELU ----------------
__global__ void k_bnfin(const float* __restrict__ sums, const float* __restrict__ sumsq,
                        float* __restrict__ mr){
  int o = blockIdx.x, t = threadIdx.x;
  float n = (o==0) ? (float)NA : (o==1) ? (float)NB : (float)NG;
  float m = sums[o*DD+t]/n;
  float v = sumsq[o*DD+t]/n - m*m;
  mr[o*2*DD + t]      = m;
  mr[o*2*DD + DD + t] = rsqrtf(fmaxf(v, 0.f) + EPS_BN);
}

__global__ __launch_bounds__(256) void k_norm(
    float* __restrict__ buf, size_t nrows,
    const float* __restrict__ mr, const float* __restrict__ gamma,
    const float* __restrict__ beta)
{
  __shared__ float sm[DD], sr[DD], sg[DD], sb[DD];
  int t = threadIdx.x;
  sm[t] = mr[t]; sr[t] = mr[DD+t]; sg[t] = gamma[t]; sb[t] = beta[t];
  __syncthreads();
  size_t total = nrows*(DD/4);
  for (size_t i = blockIdx.x*(size_t)blockDim.x + t; i < total;
       i += (size_t)gridDim.x*blockDim.x){
    int c = ((int)(i & 63))*4;
    float4 v = ((float4*)buf)[i];
    float z0 = (v.x - sm[c+0])*sr[c+0]*sg[c+0] + sb[c+0];
    float z1 = (v.y - sm[c+1])*sr[c+1]*sg[c+1] + sb[c+1];
    float z2 = (v.z - sm[c+2])*sr[c+2]*sg[c+2] + sb[c+2];
    float z3 = (v.w - sm[c+3])*sr[c+3]*sg[c+3] + sb[c+3];
    v.x = z0 > 0.f ? z0 : expm1f(z0);
    v.y = z1 > 0.f ? z1 : expm1f(z1);
    v.z = z2 > 0.f ? z2 : expm1f(z2);
    v.w = z3 > 0.f ? z3 : expm1f(z3);
    ((float4*)buf)[i] = v;
  }
}

// ================================ launcher =================================
extern "C" void kernel_launch(void* const* d_in, const int* in_sizes, int n_in,
                              void* d_out, int out_size, void* d_ws, size_t ws_size,
                              hipStream_t stream)
{
  (void)in_sizes; (void)n_in; (void)out_size;
  const float* h   = (const float*)d_in[0];
  const float* e   = (const float*)d_in[1];
  const float* u   = (const float*)d_in[2];
  const float* snn = (const float*)d_in[3];
  const float* sne = (const float*)d_in[4];
  const float* W   = (const float*)d_in[5];
  const float* b   = (const float*)d_in[6];
  const float* gamma = (const float*)d_in[7];
  const float* beta  = (const float*)d_in[8];
  const int* ba  = (const int*)d_in[9];
  const int* a2g = (const int*)d_in[10];
  const int* b2g = (const int*)d_in[11];

  float* outp  = (float*)d_out;
  float* h_pre = outp;
  float* e_pre = outp + (size_t)NA*DD;
  float* u_pre = outp + (size_t)(NA+NB)*DD;

  char* ws = (char*)d_ws;
  size_t off = 0;
  auto alloc = [&](size_t bytes)->char* {
    char* p = ws + off;
    off += (bytes + 255) & ~(size_t)255;
    return p;
  };
  unsigned short* Wbf = (unsigned short*)alloc((size_t)9*DD*DD*2);
  unsigned short* Yh  = (unsigned short*)alloc((size_t)4*NA*DD*2);
  unsigned short* Ye  = (unsigned short*)alloc((size_t)2*NB*DD*2);
  unsigned short* Yu  = (unsigned short*)alloc((size_t)3*NG*DD*2);
  unsigned short* Sg  = (unsigned short*)alloc((size_t)NB*DD*2);
  int* aoff  = (int*)alloc((size_t)(NA+1)*4);
  int* goffa = (int*)alloc((size_t)(NG+1)*4);
  int* goffb = (int*)alloc((size_t)(NG+1)*4);
  int* alist = (int*)alloc((size_t)NA*4);
  int* blist = (int*)alloc((size_t)NB*4);
  int* incb  = (int*)alloc((size_t)2*NB*4);
  int* inco  = (int*)alloc((size_t)2*NB*4);
  int* part  = (int*)alloc(1024);
  float* mr  = (float*)alloc((size_t)3*2*DD*4);
  char* zz   = ws + off;                      // ---- zero zone start ----
  int* deg      = (int*)alloc((size_t)NA*4);
  int* cur_atom = (int*)alloc((size_t)NA*4);
  int* cnta  = (int*)alloc((size_t)NG*4);
  int* cntb  = (int*)alloc((size_t)NG*4);
  int* cura  = (int*)alloc((size_t)NG*4);
  int* curb  = (int*)alloc((size_t)NG*4);
  float* sums  = (float*)alloc((size_t)3*DD*4);
  float* sumsq = (float*)alloc((size_t)3*DD*4);
  size_t zbytes = (size_t)((ws + off) - zz);

  if (ws_size < off) return;

  unsigned short* Ah = Yh;
  unsigned short* Dh = Yh + (size_t)1*NA*DD;
  unsigned short* Eh = Yh + (size_t)2*NA*DD;
  unsigned short* Gh = Yh + (size_t)3*NA*DD;
  unsigned short* Be = Ye;
  unsigned short* He = Ye + (size_t)NB*DD;
  unsigned short* Cu = Yu;
  unsigned short* Fu = Yu + (size_t)1*NG*DD;
  unsigned short* Iu = Yu + (size_t)2*NG*DD;

  k_zero<<<256, 256, 0, stream>>>((int4*)zz, zbytes/16);
  k_wconv<<<288, 256, 0, stream>>>(W, Wbf, 9*DD*DD/4);

  k_gemm8<<<(NA+95)/96, 512, 0, stream>>>(h, NA, Wbf, b, Yh, 0,3,4,6, 4);
  k_gemm8<<<(NB+95)/96, 512, 0, stream>>>(e, NB, Wbf, b, Ye, 1,7,0,0, 2);
  k_gemm8<<<(NG+95)/96, 512, 0, stream>>>(u, NG, Wbf, b, Yu, 2,5,8,0, 3);

  k_hist<<<1024, 256, 0, stream>>>(ba, b2g, a2g, deg, cntb, cnta);

  k_scan_partials<<<98, 256, 0, stream>>>(deg, NA, part);
  k_scan_small<<<1, 64, 0, stream>>>(part, 98);
  k_scan_final<<<98, 256, 0, stream>>>(deg, NA, part, aoff);
  k_scan_partials<<<5, 256, 0, stream>>>(cnta, NG, part);
  k_scan_small<<<1, 64, 0, stream>>>(part, 5);
  k_scan_final<<<5, 256, 0, stream>>>(cnta, NG, part, goffa);
  k_scan_partials<<<5, 256, 0, stream>>>(cntb, NG, part);
  k_scan_small<<<1, 64, 0, stream>>>(part, 5);
  k_scan_final<<<5, 256, 0, stream>>>(cntb, NG, part, goffb);

  k_scatter_atoms<<<512, 256, 0, stream>>>(a2g, goffa, cura, alist);
  k_scatter_bonds<<<512, 256, 0, stream>>>(ba, b2g, goffb, curb, blist,
                                           aoff, cur_atom, incb, inco);

  k_bond<<<2048, 256, 0, stream>>>(Ah, Be, Cu, ba, b2g, sne, Sg, e_pre,
                                   sums + DD, sumsq + DD);
  k_atom<<<2048, 256, 0, stream>>>(Dh, Eh, Fu, Sg, aoff, incb, inco, a2g, snn,
                                   h_pre, sums + 0, sumsq + 0);
  k_graph<<<NG, 256, 0, stream>>>(Gh, He, Iu, goffa, alist, goffb, blist, u_pre);
  k_ustats<<<40, 256, 0, stream>>>(u_pre, sums + 2*DD, sumsq + 2*DD);

  k_bnfin<<<3, 256, 0, stream>>>(sums, sumsq, mr);

  k_norm<<<2048, 256, 0, stream>>>(h_pre, (size_t)NA, mr + 0,      gamma + 0,    beta + 0);
  k_norm<<<2048, 256, 0, stream>>>(e_pre, (size_t)NB, mr + 2*DD,   gamma + DD,   beta + DD);
  k_norm<<<64,   256, 0, stream>>>(u_pre, (size_t)NG, mr + 4*DD,   gamma + 2*DD, beta + 2*DD);
}

// Round 10
// 1446.454 us; speedup vs baseline: 1.4401x; 1.0642x over previous
//
#include <hip/hip_runtime.h>
#include <stdint.h>

#define NA 200000
#define NB 300000
#define NG 10000
#define DD 256
#define EPS_GATE 1e-6f
#define EPS_BN 1e-5f

typedef short bf16x8 __attribute__((ext_vector_type(8)));
typedef float f32x4 __attribute__((ext_vector_type(4)));

__device__ __forceinline__ unsigned short f2bf(float f){
  union { float f; uint32_t u; } v; v.f = f;
  uint32_t uu = v.u;
  uint32_t r = (uu + 0x7FFFu + ((uu >> 16) & 1u)) >> 16;
  return (unsigned short)r;
}
__device__ __forceinline__ float bf2f(unsigned short s){
  union { uint32_t u; float f; } v; v.u = ((uint32_t)s) << 16; return v.f;
}

__device__ __forceinline__ void gload_lds16(const unsigned short* g, unsigned short* l){
  __builtin_amdgcn_global_load_lds(
      (const __attribute__((address_space(1))) unsigned int*)g,
      (__attribute__((address_space(3))) unsigned int*)l, 16, 0, 0);
}

// ---------------- zero fill ----------------
__global__ void k_zero(int4* p, size_t n16){
  for (size_t i = blockIdx.x*(size_t)blockDim.x + threadIdx.x; i < n16;
       i += (size_t)gridDim.x*blockDim.x)
    p[i] = make_int4(0,0,0,0);
}

// ---------------- W fp32 -> bf16 ----------------
__global__ void k_wconv(const float* __restrict__ W, unsigned short* __restrict__ Wbf, int n4){
  for (int i = blockIdx.x*blockDim.x + threadIdx.x; i < n4; i += gridDim.x*blockDim.x){
    float4 v = ((const float4*)W)[i];
    ushort4 o; o.x = f2bf(v.x); o.y = f2bf(v.y); o.z = f2bf(v.z); o.w = f2bf(v.w);
    ((ushort4*)Wbf)[i] = o;
  }
}

// ====== T3+T4 fused GEMM (R9 champion, unchanged): dbuf B + counted vmcnt ======
__global__ __launch_bounds__(512, 4) void k_gemm8(
    const float* __restrict__ x, int Nrows,
    const unsigned short* __restrict__ Wbf,
    const float* __restrict__ bias,
    unsigned short* __restrict__ Y,
    int j0, int j1, int j2, int j3, int nW)
{
  __shared__ unsigned short As[96*256];     // 48 KB
  __shared__ unsigned short Bs[2*256*32];   // 32 KB
  const int tid  = threadIdx.x;
  const int wave = tid >> 6, lane = tid & 63;
  const int l15  = lane & 15, kq = lane >> 4;
  const int wr   = wave >> 2, wc = wave & 3;
  const int rowBase = blockIdx.x * 96;

  #pragma unroll
  for (int i = 0; i < 6; ++i){
    int idx = i*512 + tid;
    int r = idx >> 5, g = idx & 31;
    f32x4 v0 = {0.f,0.f,0.f,0.f}, v1 = {0.f,0.f,0.f,0.f};
    if (rowBase + r < Nrows){
      const float* p = x + (size_t)(rowBase + r)*DD + g*8;
      v0 = *(const f32x4*)p; v1 = *(const f32x4*)(p + 4);
    }
    uint32_t d[4];
    const uint32_t* a  = (const uint32_t*)&v0;
    const uint32_t* b2 = (const uint32_t*)&v1;
    d[0] = __builtin_amdgcn_perm(a[1],  a[0],  0x07060302u);
    d[1] = __builtin_amdgcn_perm(a[3],  a[2],  0x07060302u);
    d[2] = __builtin_amdgcn_perm(b2[1], b2[0], 0x07060302u);
    d[3] = __builtin_amdgcn_perm(b2[3], b2[2], 0x07060302u);
    int gs = g ^ ((r & 15) << 1);
    *(int4*)(As + r*256 + gs*8) = *(int4*)d;
  }

  const int sB = kq ^ ((l15 >> 1) & 3);

  auto pick = [&](int jj)->int { return (jj==0) ? j0 : (jj==1) ? j1 : (jj==2) ? j2 : j3; };

  auto stageB = [&](int j, int ks, int buf){
    const unsigned short* Wj = Wbf + (size_t)j*DD*DD + ks*32;
    unsigned short* dst = Bs + (size_t)buf*(256*32);
    #pragma unroll
    for (int i = 0; i < 2; ++i){
      int idx  = i*512 + tid;
      int row  = idx >> 2;
      int slot = idx & 3;
      int srcg = slot ^ ((row >> 1) & 3);
      gload_lds16(Wj + (size_t)row*DD + srcg*8,
                  dst + ((size_t)i*512 + wave*64)*8);
    }
  };

  stageB(pick(0), 0, 0);
  __syncthreads();

  for (int jj = 0; jj < nW; ++jj){
    const int j = pick(jj);
    f32x4 acc[3][4];
    #pragma unroll
    for (int m=0;m<3;m++)
      #pragma unroll
      for (int n=0;n<4;n++)
        acc[m][n] = (f32x4){0.f,0.f,0.f,0.f};

    #pragma unroll
    for (int ks = 0; ks < 8; ++ks){
      if (ks < 7){
        stageB(j, ks+1, (ks+1)&1);
        asm volatile("s_waitcnt vmcnt(2)" ::: "memory");
      } else {
        asm volatile("s_waitcnt vmcnt(0)" ::: "memory");
      }
      __builtin_amdgcn_s_barrier();

      const unsigned short* Bb = Bs + (size_t)(ks&1)*(256*32);
      bf16x8 afr[3], bfr[4];
      #pragma unroll
      for (int m=0;m<3;m++){
        int row = wr*48 + 16*m + l15;
        int gs = (ks*4 + kq) ^ (l15 << 1);
        afr[m] = *(const bf16x8*)(As + row*256 + gs*8);
      }
      #pragma unroll
      for (int n=0;n<4;n++){
        int row = wc*64 + 16*n + l15;
        bfr[n] = *(const bf16x8*)(Bb + row*32 + sB*8);
      }
      #pragma unroll
      for (int m=0;m<3;m++)
        #pragma unroll
        for (int n=0;n<4;n++)
          acc[m][n] = __builtin_amdgcn_mfma_f32_16x16x32_bf16(afr[m], bfr[n], acc[m][n], 0,0,0);

      __builtin_amdgcn_s_barrier();
    }

    const float* bj = bias + (size_t)j*DD;
    unsigned short* Yj = Y + (size_t)jj*Nrows*DD;
    #pragma unroll
    for (int m=0;m<3;m++){
      int row0 = rowBase + wr*48 + 16*m + 4*kq;
      #pragma unroll
      for (int n=0;n<4;n++){
        int col = wc*64 + 16*n + l15;
        float bv = bj[col];
        #pragma unroll
        for (int r=0;r<4;r++){
          int row = row0 + r;
          if (row < Nrows) Yj[(size_t)row*DD + col] = f2bf(acc[m][n][r] + bv);
        }
      }
    }

    if (jj+1 < nW) stageB(pick(jj+1), 0, 0);
  }
}

// ---------------- histograms ----------------
__global__ void k_hist(const int* __restrict__ ba, const int* __restrict__ b2g,
                       const int* __restrict__ a2g,
                       int* deg, int* cntb, int* cnta){
  int stride = gridDim.x*blockDim.x;
  for (int i = blockIdx.x*blockDim.x + threadIdx.x; i < NB; i += stride){
    atomicAdd(&deg[ba[2*i]],   1);
    atomicAdd(&deg[ba[2*i+1]], 1);
    atomicAdd(&cntb[b2g[i]],   1);
  }
  for (int i = blockIdx.x*blockDim.x + threadIdx.x; i < NA; i += stride)
    atomicAdd(&cnta[a2g[i]], 1);
}

// ---------------- exclusive scan (3-phase), 2048 elems/block ----------------
__global__ void k_scan_partials(const int* __restrict__ in, int n, int* __restrict__ part){
  __shared__ int sd[256];
  int base = blockIdx.x*2048;
  int s = 0;
  #pragma unroll
  for (int i=0;i<8;i++){
    int idx = base + threadIdx.x*8 + i;
    if (idx < n) s += in[idx];
  }
  sd[threadIdx.x] = s;
  __syncthreads();
  for (int off=128; off>0; off>>=1){
    if (threadIdx.x < off) sd[threadIdx.x] += sd[threadIdx.x+off];
    __syncthreads();
  }
  if (threadIdx.x==0) part[blockIdx.x] = sd[0];
}
__global__ void k_scan_small(int* part, int nb){
  if (threadIdx.x==0 && blockIdx.x==0){
    int run = 0;
    for (int i=0;i<nb;i++){ int v = part[i]; part[i] = run; run += v; }
    part[nb] = run;
  }
}
__global__ void k_scan_final(const int* __restrict__ in, int n,
                             const int* __restrict__ part, int* __restrict__ outp){
  __shared__ int sd[256];
  int base = blockIdx.x*2048;
  int loc[8];
  int s = 0;
  #pragma unroll
  for (int i=0;i<8;i++){
    int idx = base + threadIdx.x*8 + i;
    int v = (idx < n) ? in[idx] : 0;
    loc[i] = s; s += v;
  }
  sd[threadIdx.x] = s;
  __syncthreads();
  int mine = s;
  for (int off=1; off<256; off<<=1){
    int add = (threadIdx.x >= off) ? sd[threadIdx.x - off] : 0;
    __syncthreads();
    sd[threadIdx.x] += add;
    __syncthreads();
  }
  int b0 = part[blockIdx.x] + sd[threadIdx.x] - mine;
  #pragma unroll
  for (int i=0;i<8;i++){
    int idx = base + threadIdx.x*8 + i;
    if (idx < n) outp[idx] = b0 + loc[i];
  }
  if (blockIdx.x==0 && threadIdx.x==0) outp[n] = part[gridDim.x];
}

// ---------------- scatter: graph lists + bond-incidence lists ----------------
__global__ void k_scatter_atoms(const int* __restrict__ a2g, const int* __restrict__ goffa,
                                int* cura, int* alist){
  for (int i = blockIdx.x*blockDim.x + threadIdx.x; i < NA; i += gridDim.x*blockDim.x){
    int g = a2g[i];
    int p = atomicAdd(&cura[g], 1);
    alist[goffa[g] + p] = i;
  }
}
__global__ void k_scatter_bonds(const int* __restrict__ ba, const int* __restrict__ b2g,
                                const int* __restrict__ goffb, int* curb, int* blist,
                                const int* __restrict__ aoff, int* cur_atom,
                                int* incb, int* inco){
  for (int i = blockIdx.x*blockDim.x + threadIdx.x; i < NB; i += gridDim.x*blockDim.x){
    int g = b2g[i];
    int p = atomicAdd(&curb[g], 1);
    blist[goffb[g] + p] = i;
    int i0 = ba[2*i], i1 = ba[2*i+1];
    int q0 = atomicAdd(&cur_atom[i0], 1);
    incb[aoff[i0]+q0] = i; inco[aoff[i0]+q0] = i1;
    int q1 = atomicAdd(&cur_atom[i1], 1);
    incb[aoff[i1]+q1] = i; inco[aoff[i1]+q1] = i0;
  }
}

// ------- bond kernel: e_pre stats + Sg; writes bf16(e_pre) IN PLACE over Be -------
__global__ __launch_bounds__(256) void k_bond(
    const unsigned short* __restrict__ Ah, unsigned short* __restrict__ Be, // read+overwrite
    const unsigned short* __restrict__ Cu,
    const int* __restrict__ ba, const int* __restrict__ b2g,
    const float* __restrict__ sne,
    unsigned short* __restrict__ Sg,
    float* esum, float* esumsq)
{
  const int wave = threadIdx.x >> 6, lane = threadIdx.x & 63;
  float s1[4] = {0,0,0,0}, s2[4] = {0,0,0,0};
  const int wstride = gridDim.x*4;
  for (int bond = blockIdx.x*4 + wave; bond < NB; bond += wstride){
    int i0 = ba[2*bond], i1 = ba[2*bond+1];
    int g  = b2g[bond];
    float sn = sne[bond];
    ushort4 a0 = *(const ushort4*)(Ah + (size_t)i0*DD + lane*4);
    ushort4 a1 = *(const ushort4*)(Ah + (size_t)i1*DD + lane*4);
    ushort4 be = *(const ushort4*)(Be + (size_t)bond*DD + lane*4);
    ushort4 cu = *(const ushort4*)(Cu + (size_t)g*DD + lane*4);
    float e0 = bf2f(a0.x)+bf2f(a1.x)+bf2f(be.x)+bf2f(cu.x);
    float e1 = bf2f(a0.y)+bf2f(a1.y)+bf2f(be.y)+bf2f(cu.y);
    float e2 = bf2f(a0.z)+bf2f(a1.z)+bf2f(be.z)+bf2f(cu.z);
    float e3 = bf2f(a0.w)+bf2f(a1.w)+bf2f(be.w)+bf2f(cu.w);
    ushort4 sg;
    sg.x = f2bf(1.f/(1.f+__expf(-e0)));
    sg.y = f2bf(1.f/(1.f+__expf(-e1)));
    sg.z = f2bf(1.f/(1.f+__expf(-e2)));
    sg.w = f2bf(1.f/(1.f+__expf(-e3)));
    *(ushort4*)(Sg + (size_t)bond*DD + lane*4) = sg;
    float p0 = e0*sn, p1 = e1*sn, p2 = e2*sn, p3 = e3*sn;
    ushort4 eb; eb.x = f2bf(p0); eb.y = f2bf(p1); eb.z = f2bf(p2); eb.w = f2bf(p3);
    *(ushort4*)(Be + (size_t)bond*DD + lane*4) = eb;   // in-place: own row, read-before-write
    s1[0]+=p0; s2[0]+=p0*p0;
    s1[1]+=p1; s2[1]+=p1*p1;
    s1[2]+=p2; s2[2]+=p2*p2;
    s1[3]+=p3; s2[3]+=p3*p3;
  }
  __shared__ float red[4*DD];
  #pragma unroll
  for (int c=0;c<4;c++) red[wave*DD + lane*4 + c] = s1[c];
  __syncthreads();
  if (threadIdx.x < DD){
    float t = red[threadIdx.x] + red[DD+threadIdx.x] + red[2*DD+threadIdx.x] + red[3*DD+threadIdx.x];
    atomicAdd(&esum[threadIdx.x], t);
  }
  __syncthreads();
  #pragma unroll
  for (int c=0;c<4;c++) red[wave*DD + lane*4 + c] = s2[c];
  __syncthreads();
  if (threadIdx.x < DD){
    float t = red[threadIdx.x] + red[DD+threadIdx.x] + red[2*DD+threadIdx.x] + red[3*DD+threadIdx.x];
    atomicAdd(&esumsq[threadIdx.x], t);
  }
}

// ------- atom kernel: h_pre stats; writes bf16(h_pre) IN PLACE over Dh -------
__global__ __launch_bounds__(256) void k_atom(
    unsigned short* __restrict__ Dh,                    // read+overwrite (own row only)
    const unsigned short* __restrict__ Eh,
    const unsigned short* __restrict__ Fu, const unsigned short* __restrict__ Sg,
    const int* __restrict__ aoff, const int* __restrict__ incb, const int* __restrict__ inco,
    const int* __restrict__ a2g, const float* __restrict__ snn,
    float* hsum, float* hsumsq)
{
  const int wave = threadIdx.x >> 6, lane = threadIdx.x & 63;
  float s1[4] = {0,0,0,0}, s2[4] = {0,0,0,0};
  const int wstride = gridDim.x*4;
  for (int a = blockIdx.x*4 + wave; a < NA; a += wstride){
    int j0 = aoff[a], j1 = aoff[a+1];
    float num[4] = {0,0,0,0}, den[4] = {0,0,0,0};
    for (int j = j0; j < j1; ++j){
      int bond = incb[j], other = inco[j];
      ushort4 sg = *(const ushort4*)(Sg + (size_t)bond*DD + lane*4);
      ushort4 eo = *(const ushort4*)(Eh + (size_t)other*DD + lane*4);
      float g0 = bf2f(sg.x), g1 = bf2f(sg.y), g2 = bf2f(sg.z), g3 = bf2f(sg.w);
      num[0] += g0*bf2f(eo.x); num[1] += g1*bf2f(eo.y);
      num[2] += g2*bf2f(eo.z); num[3] += g3*bf2f(eo.w);
      den[0] += g0; den[1] += g1; den[2] += g2; den[3] += g3;
    }
    int g = a2g[a]; float sn = snn[a];
    ushort4 dh = *(const ushort4*)(Dh + (size_t)a*DD + lane*4);
    ushort4 fu = *(const ushort4*)(Fu + (size_t)g*DD + lane*4);
    float h0 = (bf2f(dh.x) + num[0]/(den[0]+EPS_GATE) + bf2f(fu.x))*sn;
    float h1 = (bf2f(dh.y) + num[1]/(den[1]+EPS_GATE) + bf2f(fu.y))*sn;
    float h2 = (bf2f(dh.z) + num[2]/(den[2]+EPS_GATE) + bf2f(fu.z))*sn;
    float h3 = (bf2f(dh.w) + num[3]/(den[3]+EPS_GATE) + bf2f(fu.w))*sn;
    ushort4 hb; hb.x = f2bf(h0); hb.y = f2bf(h1); hb.z = f2bf(h2); hb.w = f2bf(h3);
    *(ushort4*)(Dh + (size_t)a*DD + lane*4) = hb;      // in-place: own row
    s1[0]+=h0; s2[0]+=h0*h0;
    s1[1]+=h1; s2[1]+=h1*h1;
    s1[2]+=h2; s2[2]+=h2*h2;
    s1[3]+=h3; s2[3]+=h3*h3;
  }
  __shared__ float red[4*DD];
  #pragma unroll
  for (int c=0;c<4;c++) red[wave*DD + lane*4 + c] = s1[c];
  __syncthreads();
  if (threadIdx.x < DD){
    float t = red[threadIdx.x] + red[DD+threadIdx.x] + red[2*DD+threadIdx.x] + red[3*DD+threadIdx.x];
    atomicAdd(&hsum[threadIdx.x], t);
  }
  __syncthreads();
  #pragma unroll
  for (int c=0;c<4;c++) red[wave*DD + lane*4 + c] = s2[c];
  __syncthreads();
  if (threadIdx.x < DD){
    float t = red[threadIdx.x] + red[DD+threadIdx.x] + red[2*DD+threadIdx.x] + red[3*DD+threadIdx.x];
    atomicAdd(&hsumsq[threadIdx.x], t);
  }
}

// ---------------- graph kernel: u_pre per graph (block per graph) ------------------
__global__ __launch_bounds__(256) void k_graph(
    const unsigned short* __restrict__ Gh, const unsigned short* __restrict__ He,
    const unsigned short* __restrict__ Iu,
    const int* __restrict__ goffa, const int* __restrict__ alist,
    const int* __restrict__ goffb, const int* __restrict__ blist,
    float* __restrict__ u_pre)
{
  int g = blockIdx.x, t = threadIdx.x;
  int a0 = goffa[g], a1 = goffa[g+1];
  float sA = 0.f;
  for (int i = a0; i < a1; ++i) sA += bf2f(Gh[(size_t)alist[i]*DD + t]);
  int b0 = goffb[g], b1 = goffb[g+1];
  float sB = 0.f;
  for (int i = b0; i < b1; ++i) sB += bf2f(He[(size_t)blist[i]*DD + t]);
  float cA = (float)max(a1 - a0, 1);
  float cB = (float)max(b1 - b0, 1);
  u_pre[(size_t)g*DD + t] = sA/cA + sB/cB + bf2f(Iu[(size_t)g*DD + t]);
}

__global__ void k_ustats(const float* __restrict__ u_pre, float* usum, float* usumsq){
  int t = threadIdx.x;
  float s = 0.f, s2 = 0.f;
  for (int g = blockIdx.x; g < NG; g += gridDim.x){
    float v = u_pre[(size_t)g*DD + t];
    s += v; s2 += v*v;
  }
  atomicAdd(&usum[t], s);
  atomicAdd(&usumsq[t], s2);
}

// ---------------- BN finalize + normalize/ELU ----------------
__global__ void k_bnfin(const float* __restrict__ sums, const float* __restrict__ sumsq,
                        float* __restrict__ mr){
  int o = blockIdx.x, t = threadIdx.x;
  float n = (o==0) ? (float)NA : (o==1) ? (float)NB : (float)NG;
  float m = sums[o*DD+t]/n;
  float v = sumsq[o*DD+t]/n - m*m;
  mr[o*2*DD + t]      = m;
  mr[o*2*DD + DD + t] = rsqrtf(fmaxf(v, 0.f) + EPS_BN);
}

// normalize bf16 src -> fp32 dst (h, e)
__global__ __launch_bounds__(256) void k_norm_bf(
    const unsigned short* __restrict__ src, float* __restrict__ dst, size_t nrows,
    const float* __restrict__ mr, const float* __restrict__ gamma,
    const float* __restrict__ beta)
{
  __shared__ float sm[DD], sr[DD], sg[DD], sb[DD];
  int t = threadIdx.x;
  sm[t] = mr[t]; sr[t] = mr[DD+t]; sg[t] = gamma[t]; sb[t] = beta[t];
  __syncthreads();
  size_t total = nrows*(DD/4);
  for (size_t i = blockIdx.x*(size_t)blockDim.x + t; i < total;
       i += (size_t)gridDim.x*blockDim.x){
    int c = ((int)(i & 63))*4;
    ushort4 s = ((const ushort4*)src)[i];
    float z0 = (bf2f(s.x) - sm[c+0])*sr[c+0]*sg[c+0] + sb[c+0];
    float z1 = (bf2f(s.y) - sm[c+1])*sr[c+1]*sg[c+1] + sb[c+1];
    float z2 = (bf2f(s.z) - sm[c+2])*sr[c+2]*sg[c+2] + sb[c+2];
    float z3 = (bf2f(s.w) - sm[c+3])*sr[c+3]*sg[c+3] + sb[c+3];
    float4 v;
    v.x = z0 > 0.f ? z0 : expm1f(z0);
    v.y = z1 > 0.f ? z1 : expm1f(z1);
    v.z = z2 > 0.f ? z2 : expm1f(z2);
    v.w = z3 > 0.f ? z3 : expm1f(z3);
    ((float4*)dst)[i] = v;
  }
}

// normalize fp32 in-place (u)
__global__ __launch_bounds__(256) void k_norm_f32(
    float* __restrict__ buf, size_t nrows,
    const float* __restrict__ mr, const float* __restrict__ gamma,
    const float* __restrict__ beta)
{
  __shared__ float sm[DD], sr[DD], sg[DD], sb[DD];
  int t = threadIdx.x;
  sm[t] = mr[t]; sr[t] = mr[DD+t]; sg[t] = gamma[t]; sb[t] = beta[t];
  __syncthreads();
  size_t total = nrows*(DD/4);
  for (size_t i = blockIdx.x*(size_t)blockDim.x + t; i < total;
       i += (size_t)gridDim.x*blockDim.x){
    int c = ((int)(i & 63))*4;
    float4 v = ((float4*)buf)[i];
    float z0 = (v.x - sm[c+0])*sr[c+0]*sg[c+0] + sb[c+0];
    float z1 = (v.y - sm[c+1])*sr[c+1]*sg[c+1] + sb[c+1];
    float z2 = (v.z - sm[c+2])*sr[c+2]*sg[c+2] + sb[c+2];
    float z3 = (v.w - sm[c+3])*sr[c+3]*sg[c+3] + sb[c+3];
    v.x = z0 > 0.f ? z0 : expm1f(z0);
    v.y = z1 > 0.f ? z1 : expm1f(z1);
    v.z = z2 > 0.f ? z2 : expm1f(z2);
    v.w = z3 > 0.f ? z3 : expm1f(z3);
    ((float4*)buf)[i] = v;
  }
}

// ================================ launcher =================================
extern "C" void kernel_launch(void* const* d_in, const int* in_sizes, int n_in,
                              void* d_out, int out_size, void* d_ws, size_t ws_size,
                              hipStream_t stream)
{
  (void)in_sizes; (void)n_in; (void)out_size;
  const float* h   = (const float*)d_in[0];
  const float* e   = (const float*)d_in[1];
  const float* u   = (const float*)d_in[2];
  const float* snn = (const float*)d_in[3];
  const float* sne = (const float*)d_in[4];
  const float* W   = (const float*)d_in[5];
  const float* b   = (const float*)d_in[6];
  const float* gamma = (const float*)d_in[7];
  const float* beta  = (const float*)d_in[8];
  const int* ba  = (const int*)d_in[9];
  const int* a2g = (const int*)d_in[10];
  const int* b2g = (const int*)d_in[11];

  float* outp  = (float*)d_out;
  float* h_out = outp;
  float* e_out = outp + (size_t)NA*DD;
  float* u_pre = outp + (size_t)(NA+NB)*DD;

  char* ws = (char*)d_ws;
  size_t off = 0;
  auto alloc = [&](size_t bytes)->char* {
    char* p = ws + off;
    off += (bytes + 255) & ~(size_t)255;
    return p;
  };
  unsigned short* Wbf = (unsigned short*)alloc((size_t)9*DD*DD*2);
  unsigned short* Yh  = (unsigned short*)alloc((size_t)4*NA*DD*2);
  unsigned short* Ye  = (unsigned short*)alloc((size_t)2*NB*DD*2);
  unsigned short* Yu  = (unsigned short*)alloc((size_t)3*NG*DD*2);
  unsigned short* Sg  = (unsigned short*)alloc((size_t)NB*DD*2);
  int* aoff  = (int*)alloc((size_t)(NA+1)*4);
  int* goffa = (int*)alloc((size_t)(NG+1)*4);
  int* goffb = (int*)alloc((size_t)(NG+1)*4);
  int* alist = (int*)alloc((size_t)NA*4);
  int* blist = (int*)alloc((size_t)NB*4);
  int* incb  = (int*)alloc((size_t)2*NB*4);
  int* inco  = (int*)alloc((size_t)2*NB*4);
  int* part  = (int*)alloc(1024);
  float* mr  = (float*)alloc((size_t)3*2*DD*4);
  char* zz   = ws + off;                      // ---- zero zone start ----
  int* deg      = (int*)alloc((size_t)NA*4);
  int* cur_atom = (int*)alloc((size_t)NA*4);
  int* cnta  = (int*)alloc((size_t)NG*4);
  int* cntb  = (int*)alloc((size_t)NG*4);
  int* cura  = (int*)alloc((size_t)NG*4);
  int* curb  = (int*)alloc((size_t)NG*4);
  float* sums  = (float*)alloc((size_t)3*DD*4);
  float* sumsq = (float*)alloc((size_t)3*DD*4);
  size_t zbytes = (size_t)((ws + off) - zz);

  if (ws_size < off) return;

  unsigned short* Ah = Yh;
  unsigned short* Dh = Yh + (size_t)1*NA*DD;   // becomes bf16(h_pre) after k_atom
  unsigned short* Eh = Yh + (size_t)2*NA*DD;
  unsigned short* Gh = Yh + (size_t)3*NA*DD;
  unsigned short* Be = Ye;                     // becomes bf16(e_pre) after k_bond
  unsigned short* He = Ye + (size_t)NB*DD;
  unsigned short* Cu = Yu;
  unsigned short* Fu = Yu + (size_t)1*NG*DD;
  unsigned short* Iu = Yu + (size_t)2*NG*DD;

  k_zero<<<256, 256, 0, stream>>>((int4*)zz, zbytes/16);
  k_wconv<<<288, 256, 0, stream>>>(W, Wbf, 9*DD*DD/4);

  k_gemm8<<<(NA+95)/96, 512, 0, stream>>>(h, NA, Wbf, b, Yh, 0,3,4,6, 4);
  k_gemm8<<<(NB+95)/96, 512, 0, stream>>>(e, NB, Wbf, b, Ye, 1,7,0,0, 2);
  k_gemm8<<<(NG+95)/96, 512, 0, stream>>>(u, NG, Wbf, b, Yu, 2,5,8,0, 3);

  k_hist<<<1024, 256, 0, stream>>>(ba, b2g, a2g, deg, cntb, cnta);

  k_scan_partials<<<98, 256, 0, stream>>>(deg, NA, part);
  k_scan_small<<<1, 64, 0, stream>>>(part, 98);
  k_scan_final<<<98, 256, 0, stream>>>(deg, NA, part, aoff);
  k_scan_partials<<<5, 256, 0, stream>>>(cnta, NG, part);
  k_scan_small<<<1, 64, 0, stream>>>(part, 5);
  k_scan_final<<<5, 256, 0, stream>>>(cnta, NG, part, goffa);
  k_scan_partials<<<5, 256, 0, stream>>>(cntb, NG, part);
  k_scan_small<<<1, 64, 0, stream>>>(part, 5);
  k_scan_final<<<5, 256, 0, stream>>>(cntb, NG, part, goffb);

  k_scatter_atoms<<<512, 256, 0, stream>>>(a2g, goffa, cura, alist);
  k_scatter_bonds<<<512, 256, 0, stream>>>(ba, b2g, goffb, curb, blist,
                                           aoff, cur_atom, incb, inco);

  k_bond<<<2048, 256, 0, stream>>>(Ah, Be, Cu, ba, b2g, sne, Sg,
                                   sums + DD, sumsq + DD);
  k_atom<<<2048, 256, 0, stream>>>(Dh, Eh, Fu, Sg, aoff, incb, inco, a2g, snn,
                                   sums + 0, sumsq + 0);
  k_graph<<<NG, 256, 0, stream>>>(Gh, He, Iu, goffa, alist, goffb, blist, u_pre);
  k_ustats<<<40, 256, 0, stream>>>(u_pre, sums + 2*DD, sumsq + 2*DD);

  k_bnfin<<<3, 256, 0, stream>>>(sums, sumsq, mr);

  k_norm_bf<<<2048, 256, 0, stream>>>(Dh, h_out, (size_t)NA, mr + 0,    gamma + 0,    beta + 0);
  k_norm_bf<<<2048, 256, 0, stream>>>(Be, e_out, (size_t)NB, mr + 2*DD, gamma + DD,   beta + DD);
  k_norm_f32<<<64,  256, 0, stream>>>(u_pre, (size_t)NG, mr + 4*DD,     gamma + 2*DD, beta + 2*DD);
}

// Round 11
// 1347.447 us; speedup vs baseline: 1.5459x; 1.0735x over previous
//
#include <hip/hip_runtime.h>
#include <stdint.h>

#define NA 200000
#define NB 300000
#define NG 10000
#define DD 256
#define EPS_GATE 1e-6f
#define EPS_BN 1e-5f

typedef short bf16x8 __attribute__((ext_vector_type(8)));
typedef float f32x4 __attribute__((ext_vector_type(4)));

__device__ __forceinline__ unsigned short f2bf(float f){
  union { float f; uint32_t u; } v; v.f = f;
  uint32_t uu = v.u;
  uint32_t r = (uu + 0x7FFFu + ((uu >> 16) & 1u)) >> 16;
  return (unsigned short)r;
}
__device__ __forceinline__ float bf2f(unsigned short s){
  union { uint32_t u; float f; } v; v.u = ((uint32_t)s) << 16; return v.f;
}

__device__ __forceinline__ void gload_lds16(const unsigned short* g, unsigned short* l){
  __builtin_amdgcn_global_load_lds(
      (const __attribute__((address_space(1))) unsigned int*)g,
      (__attribute__((address_space(3))) unsigned int*)l, 16, 0, 0);
}

// ---------------- zero fill ----------------
__global__ void k_zero(int4* p, size_t n16){
  for (size_t i = blockIdx.x*(size_t)blockDim.x + threadIdx.x; i < n16;
       i += (size_t)gridDim.x*blockDim.x)
    p[i] = make_int4(0,0,0,0);
}

// ---------------- W fp32 -> bf16 ----------------
__global__ void k_wconv(const float* __restrict__ W, unsigned short* __restrict__ Wbf, int n4){
  for (int i = blockIdx.x*blockDim.x + threadIdx.x; i < n4; i += gridDim.x*blockDim.x){
    float4 v = ((const float4*)W)[i];
    ushort4 o; o.x = f2bf(v.x); o.y = f2bf(v.y); o.z = f2bf(v.z); o.w = f2bf(v.w);
    ((ushort4*)Wbf)[i] = o;
  }
}

// ====== T3+T4 fused GEMM (R9 champion, unchanged): dbuf B + counted vmcnt ======
__global__ __launch_bounds__(512, 4) void k_gemm8(
    const float* __restrict__ x, int Nrows,
    const unsigned short* __restrict__ Wbf,
    const float* __restrict__ bias,
    unsigned short* __restrict__ Y,
    int j0, int j1, int j2, int j3, int nW)
{
  __shared__ unsigned short As[96*256];     // 48 KB
  __shared__ unsigned short Bs[2*256*32];   // 32 KB
  const int tid  = threadIdx.x;
  const int wave = tid >> 6, lane = tid & 63;
  const int l15  = lane & 15, kq = lane >> 4;
  const int wr   = wave >> 2, wc = wave & 3;
  const int rowBase = blockIdx.x * 96;

  #pragma unroll
  for (int i = 0; i < 6; ++i){
    int idx = i*512 + tid;
    int r = idx >> 5, g = idx & 31;
    f32x4 v0 = {0.f,0.f,0.f,0.f}, v1 = {0.f,0.f,0.f,0.f};
    if (rowBase + r < Nrows){
      const float* p = x + (size_t)(rowBase + r)*DD + g*8;
      v0 = *(const f32x4*)p; v1 = *(const f32x4*)(p + 4);
    }
    uint32_t d[4];
    const uint32_t* a  = (const uint32_t*)&v0;
    const uint32_t* b2 = (const uint32_t*)&v1;
    d[0] = __builtin_amdgcn_perm(a[1],  a[0],  0x07060302u);
    d[1] = __builtin_amdgcn_perm(a[3],  a[2],  0x07060302u);
    d[2] = __builtin_amdgcn_perm(b2[1], b2[0], 0x07060302u);
    d[3] = __builtin_amdgcn_perm(b2[3], b2[2], 0x07060302u);
    int gs = g ^ ((r & 15) << 1);
    *(int4*)(As + r*256 + gs*8) = *(int4*)d;
  }

  const int sB = kq ^ ((l15 >> 1) & 3);

  auto pick = [&](int jj)->int { return (jj==0) ? j0 : (jj==1) ? j1 : (jj==2) ? j2 : j3; };

  auto stageB = [&](int j, int ks, int buf){
    const unsigned short* Wj = Wbf + (size_t)j*DD*DD + ks*32;
    unsigned short* dst = Bs + (size_t)buf*(256*32);
    #pragma unroll
    for (int i = 0; i < 2; ++i){
      int idx  = i*512 + tid;
      int row  = idx >> 2;
      int slot = idx & 3;
      int srcg = slot ^ ((row >> 1) & 3);
      gload_lds16(Wj + (size_t)row*DD + srcg*8,
                  dst + ((size_t)i*512 + wave*64)*8);
    }
  };

  stageB(pick(0), 0, 0);
  __syncthreads();

  for (int jj = 0; jj < nW; ++jj){
    const int j = pick(jj);
    f32x4 acc[3][4];
    #pragma unroll
    for (int m=0;m<3;m++)
      #pragma unroll
      for (int n=0;n<4;n++)
        acc[m][n] = (f32x4){0.f,0.f,0.f,0.f};

    #pragma unroll
    for (int ks = 0; ks < 8; ++ks){
      if (ks < 7){
        stageB(j, ks+1, (ks+1)&1);
        asm volatile("s_waitcnt vmcnt(2)" ::: "memory");
      } else {
        asm volatile("s_waitcnt vmcnt(0)" ::: "memory");
      }
      __builtin_amdgcn_s_barrier();

      const unsigned short* Bb = Bs + (size_t)(ks&1)*(256*32);
      bf16x8 afr[3], bfr[4];
      #pragma unroll
      for (int m=0;m<3;m++){
        int row = wr*48 + 16*m + l15;
        int gs = (ks*4 + kq) ^ (l15 << 1);
        afr[m] = *(const bf16x8*)(As + row*256 + gs*8);
      }
      #pragma unroll
      for (int n=0;n<4;n++){
        int row = wc*64 + 16*n + l15;
        bfr[n] = *(const bf16x8*)(Bb + row*32 + sB*8);
      }
      #pragma unroll
      for (int m=0;m<3;m++)
        #pragma unroll
        for (int n=0;n<4;n++)
          acc[m][n] = __builtin_amdgcn_mfma_f32_16x16x32_bf16(afr[m], bfr[n], acc[m][n], 0,0,0);

      __builtin_amdgcn_s_barrier();
    }

    const float* bj = bias + (size_t)j*DD;
    unsigned short* Yj = Y + (size_t)jj*Nrows*DD;
    #pragma unroll
    for (int m=0;m<3;m++){
      int row0 = rowBase + wr*48 + 16*m + 4*kq;
      #pragma unroll
      for (int n=0;n<4;n++){
        int col = wc*64 + 16*n + l15;
        float bv = bj[col];
        #pragma unroll
        for (int r=0;r<4;r++){
          int row = row0 + r;
          if (row < Nrows) Yj[(size_t)row*DD + col] = f2bf(acc[m][n][r] + bv);
        }
      }
    }

    if (jj+1 < nW) stageB(pick(jj+1), 0, 0);
  }
}

// ---------------- histograms ----------------
__global__ void k_hist(const int* __restrict__ ba, const int* __restrict__ b2g,
                       const int* __restrict__ a2g,
                       int* deg, int* cntb, int* cnta){
  int stride = gridDim.x*blockDim.x;
  for (int i = blockIdx.x*blockDim.x + threadIdx.x; i < NB; i += stride){
    atomicAdd(&deg[ba[2*i]],   1);
    atomicAdd(&deg[ba[2*i+1]], 1);
    atomicAdd(&cntb[b2g[i]],   1);
  }
  for (int i = blockIdx.x*blockDim.x + threadIdx.x; i < NA; i += stride)
    atomicAdd(&cnta[a2g[i]], 1);
}

// ---------------- exclusive scan (3-phase), 2048 elems/block ----------------
__global__ void k_scan_partials(const int* __restrict__ in, int n, int* __restrict__ part){
  __shared__ int sd[256];
  int base = blockIdx.x*2048;
  int s = 0;
  #pragma unroll
  for (int i=0;i<8;i++){
    int idx = base + threadIdx.x*8 + i;
    if (idx < n) s += in[idx];
  }
  sd[threadIdx.x] = s;
  __syncthreads();
  for (int off=128; off>0; off>>=1){
    if (threadIdx.x < off) sd[threadIdx.x] += sd[threadIdx.x+off];
    __syncthreads();
  }
  if (threadIdx.x==0) part[blockIdx.x] = sd[0];
}
__global__ void k_scan_small(int* part, int nb){
  if (threadIdx.x==0 && blockIdx.x==0){
    int run = 0;
    for (int i=0;i<nb;i++){ int v = part[i]; part[i] = run; run += v; }
    part[nb] = run;
  }
}
__global__ void k_scan_final(const int* __restrict__ in, int n,
                             const int* __restrict__ part, int* __restrict__ outp){
  __shared__ int sd[256];
  int base = blockIdx.x*2048;
  int loc[8];
  int s = 0;
  #pragma unroll
  for (int i=0;i<8;i++){
    int idx = base + threadIdx.x*8 + i;
    int v = (idx < n) ? in[idx] : 0;
    loc[i] = s; s += v;
  }
  sd[threadIdx.x] = s;
  __syncthreads();
  int mine = s;
  for (int off=1; off<256; off<<=1){
    int add = (threadIdx.x >= off) ? sd[threadIdx.x - off] : 0;
    __syncthreads();
    sd[threadIdx.x] += add;
    __syncthreads();
  }
  int b0 = part[blockIdx.x] + sd[threadIdx.x] - mine;
  #pragma unroll
  for (int i=0;i<8;i++){
    int idx = base + threadIdx.x*8 + i;
    if (idx < n) outp[idx] = b0 + loc[i];
  }
  if (blockIdx.x==0 && threadIdx.x==0) outp[n] = part[gridDim.x];
}

// ---------------- scatter: graph lists + bond-incidence lists ----------------
__global__ void k_scatter_atoms(const int* __restrict__ a2g, const int* __restrict__ goffa,
                                int* cura, int* alist){
  for (int i = blockIdx.x*blockDim.x + threadIdx.x; i < NA; i += gridDim.x*blockDim.x){
    int g = a2g[i];
    int p = atomicAdd(&cura[g], 1);
    alist[goffa[g] + p] = i;
  }
}
__global__ void k_scatter_bonds(const int* __restrict__ ba, const int* __restrict__ b2g,
                                const int* __restrict__ goffb, int* curb, int* blist,
                                const int* __restrict__ aoff, int* cur_atom,
                                int* incb, int* inco){
  for (int i = blockIdx.x*blockDim.x + threadIdx.x; i < NB; i += gridDim.x*blockDim.x){
    int g = b2g[i];
    int p = atomicAdd(&curb[g], 1);
    blist[goffb[g] + p] = i;
    int i0 = ba[2*i], i1 = ba[2*i+1];
    int q0 = atomicAdd(&cur_atom[i0], 1);
    incb[aoff[i0]+q0] = i; inco[aoff[i0]+q0] = i1;
    int q1 = atomicAdd(&cur_atom[i1], 1);
    incb[aoff[i1]+q1] = i; inco[aoff[i1]+q1] = i0;
  }
}

// ------- bond kernel: 2 bonds per wave-iteration (2x gather MLP) -------
__global__ __launch_bounds__(256) void k_bond(
    const unsigned short* __restrict__ Ah, unsigned short* __restrict__ Be, // read+overwrite
    const unsigned short* __restrict__ Cu,
    const int* __restrict__ ba, const int* __restrict__ b2g,
    const float* __restrict__ sne,
    unsigned short* __restrict__ Sg,
    float* esum, float* esumsq)
{
  const int wave = threadIdx.x >> 6, lane = threadIdx.x & 63;
  float s1[4] = {0,0,0,0}, s2[4] = {0,0,0,0};
  const int wstride = gridDim.x*4;

  for (int bond = blockIdx.x*4 + wave; bond < NB; bond += 2*wstride){
    const int bondB = bond + wstride;
    const bool hasB = bondB < NB;
    const int bB = hasB ? bondB : bond;

    int i0  = ba[2*bond], i1  = ba[2*bond+1];
    int i0B = ba[2*bB],   i1B = ba[2*bB+1];
    int g   = b2g[bond],  gB  = b2g[bB];
    float sn = sne[bond], snB = sne[bB];

    // issue all 8 row-gathers before any math
    ushort4 a0  = *(const ushort4*)(Ah + (size_t)i0 *DD + lane*4);
    ushort4 a1  = *(const ushort4*)(Ah + (size_t)i1 *DD + lane*4);
    ushort4 be  = *(const ushort4*)(Be + (size_t)bond*DD + lane*4);
    ushort4 cu  = *(const ushort4*)(Cu + (size_t)g  *DD + lane*4);
    ushort4 a0B = *(const ushort4*)(Ah + (size_t)i0B*DD + lane*4);
    ushort4 a1B = *(const ushort4*)(Ah + (size_t)i1B*DD + lane*4);
    ushort4 beB = *(const ushort4*)(Be + (size_t)bB *DD + lane*4);
    ushort4 cuB = *(const ushort4*)(Cu + (size_t)gB *DD + lane*4);

    {
      float e0 = bf2f(a0.x)+bf2f(a1.x)+bf2f(be.x)+bf2f(cu.x);
      float e1 = bf2f(a0.y)+bf2f(a1.y)+bf2f(be.y)+bf2f(cu.y);
      float e2 = bf2f(a0.z)+bf2f(a1.z)+bf2f(be.z)+bf2f(cu.z);
      float e3 = bf2f(a0.w)+bf2f(a1.w)+bf2f(be.w)+bf2f(cu.w);
      ushort4 sg;
      sg.x = f2bf(1.f/(1.f+__expf(-e0)));
      sg.y = f2bf(1.f/(1.f+__expf(-e1)));
      sg.z = f2bf(1.f/(1.f+__expf(-e2)));
      sg.w = f2bf(1.f/(1.f+__expf(-e3)));
      *(ushort4*)(Sg + (size_t)bond*DD + lane*4) = sg;
      float p0 = e0*sn, p1 = e1*sn, p2 = e2*sn, p3 = e3*sn;
      ushort4 eb; eb.x = f2bf(p0); eb.y = f2bf(p1); eb.z = f2bf(p2); eb.w = f2bf(p3);
      *(ushort4*)(Be + (size_t)bond*DD + lane*4) = eb;
      s1[0]+=p0; s2[0]+=p0*p0;  s1[1]+=p1; s2[1]+=p1*p1;
      s1[2]+=p2; s2[2]+=p2*p2;  s1[3]+=p3; s2[3]+=p3*p3;
    }
    if (hasB){
      float e0 = bf2f(a0B.x)+bf2f(a1B.x)+bf2f(beB.x)+bf2f(cuB.x);
      float e1 = bf2f(a0B.y)+bf2f(a1B.y)+bf2f(beB.y)+bf2f(cuB.y);
      float e2 = bf2f(a0B.z)+bf2f(a1B.z)+bf2f(beB.z)+bf2f(cuB.z);
      float e3 = bf2f(a0B.w)+bf2f(a1B.w)+bf2f(beB.w)+bf2f(cuB.w);
      ushort4 sg;
      sg.x = f2bf(1.f/(1.f+__expf(-e0)));
      sg.y = f2bf(1.f/(1.f+__expf(-e1)));
      sg.z = f2bf(1.f/(1.f+__expf(-e2)));
      sg.w = f2bf(1.f/(1.f+__expf(-e3)));
      *(ushort4*)(Sg + (size_t)bB*DD + lane*4) = sg;
      float p0 = e0*snB, p1 = e1*snB, p2 = e2*snB, p3 = e3*snB;
      ushort4 eb; eb.x = f2bf(p0); eb.y = f2bf(p1); eb.z = f2bf(p2); eb.w = f2bf(p3);
      *(ushort4*)(Be + (size_t)bB*DD + lane*4) = eb;
      s1[0]+=p0; s2[0]+=p0*p0;  s1[1]+=p1; s2[1]+=p1*p1;
      s1[2]+=p2; s2[2]+=p2*p2;  s1[3]+=p3; s2[3]+=p3*p3;
    }
  }
  __shared__ float red[4*DD];
  #pragma unroll
  for (int c=0;c<4;c++) red[wave*DD + lane*4 + c] = s1[c];
  __syncthreads();
  if (threadIdx.x < DD){
    float t = red[threadIdx.x] + red[DD+threadIdx.x] + red[2*DD+threadIdx.x] + red[3*DD+threadIdx.x];
    atomicAdd(&esum[threadIdx.x], t);
  }
  __syncthreads();
  #pragma unroll
  for (int c=0;c<4;c++) red[wave*DD + lane*4 + c] = s2[c];
  __syncthreads();
  if (threadIdx.x < DD){
    float t = red[threadIdx.x] + red[DD+threadIdx.x] + red[2*DD+threadIdx.x] + red[3*DD+threadIdx.x];
    atomicAdd(&esumsq[threadIdx.x], t);
  }
}

// ------- atom kernel: incidence loop unrolled x2 (2x gather MLP), hoisted tail loads -------
__global__ __launch_bounds__(256) void k_atom(
    unsigned short* __restrict__ Dh,                    // read+overwrite (own row only)
    const unsigned short* __restrict__ Eh,
    const unsigned short* __restrict__ Fu, const unsigned short* __restrict__ Sg,
    const int* __restrict__ aoff, const int* __restrict__ incb, const int* __restrict__ inco,
    const int* __restrict__ a2g, const float* __restrict__ snn,
    float* hsum, float* hsumsq)
{
  const int wave = threadIdx.x >> 6, lane = threadIdx.x & 63;
  float s1[4] = {0,0,0,0}, s2[4] = {0,0,0,0};
  const int wstride = gridDim.x*4;
  for (int a = blockIdx.x*4 + wave; a < NA; a += wstride){
    int j0 = aoff[a], j1 = aoff[a+1];
    // hoist own-row / graph-row loads: they fly under the gather loop
    int g = a2g[a]; float sn = snn[a];
    ushort4 dh = *(const ushort4*)(Dh + (size_t)a*DD + lane*4);
    ushort4 fu = *(const ushort4*)(Fu + (size_t)g*DD + lane*4);

    float num[4] = {0,0,0,0}, den[4] = {0,0,0,0};
    int j = j0;
    for (; j + 2 <= j1; j += 2){
      int b0 = incb[j],   o0 = inco[j];
      int b1 = incb[j+1], o1 = inco[j+1];
      ushort4 sg0 = *(const ushort4*)(Sg + (size_t)b0*DD + lane*4);
      ushort4 eo0 = *(const ushort4*)(Eh + (size_t)o0*DD + lane*4);
      ushort4 sg1 = *(const ushort4*)(Sg + (size_t)b1*DD + lane*4);
      ushort4 eo1 = *(const ushort4*)(Eh + (size_t)o1*DD + lane*4);
      float g0 = bf2f(sg0.x), g1 = bf2f(sg0.y), g2 = bf2f(sg0.z), g3 = bf2f(sg0.w);
      num[0] += g0*bf2f(eo0.x); num[1] += g1*bf2f(eo0.y);
      num[2] += g2*bf2f(eo0.z); num[3] += g3*bf2f(eo0.w);
      den[0] += g0; den[1] += g1; den[2] += g2; den[3] += g3;
      float h0 = bf2f(sg1.x), h1 = bf2f(sg1.y), h2 = bf2f(sg1.z), h3 = bf2f(sg1.w);
      num[0] += h0*bf2f(eo1.x); num[1] += h1*bf2f(eo1.y);
      num[2] += h2*bf2f(eo1.z); num[3] += h3*bf2f(eo1.w);
      den[0] += h0; den[1] += h1; den[2] += h2; den[3] += h3;
    }
    if (j < j1){
      int b0 = incb[j], o0 = inco[j];
      ushort4 sg0 = *(const ushort4*)(Sg + (size_t)b0*DD + lane*4);
      ushort4 eo0 = *(const ushort4*)(Eh + (size_t)o0*DD + lane*4);
      float g0 = bf2f(sg0.x), g1 = bf2f(sg0.y), g2 = bf2f(sg0.z), g3 = bf2f(sg0.w);
      num[0] += g0*bf2f(eo0.x); num[1] += g1*bf2f(eo0.y);
      num[2] += g2*bf2f(eo0.z); num[3] += g3*bf2f(eo0.w);
      den[0] += g0; den[1] += g1; den[2] += g2; den[3] += g3;
    }

    float h0 = (bf2f(dh.x) + num[0]/(den[0]+EPS_GATE) + bf2f(fu.x))*sn;
    float h1 = (bf2f(dh.y) + num[1]/(den[1]+EPS_GATE) + bf2f(fu.y))*sn;
    float h2 = (bf2f(dh.z) + num[2]/(den[2]+EPS_GATE) + bf2f(fu.z))*sn;
    float h3 = (bf2f(dh.w) + num[3]/(den[3]+EPS_GATE) + bf2f(fu.w))*sn;
    ushort4 hb; hb.x = f2bf(h0); hb.y = f2bf(h1); hb.z = f2bf(h2); hb.w = f2bf(h3);
    *(ushort4*)(Dh + (size_t)a*DD + lane*4) = hb;      // in-place: own row
    s1[0]+=h0; s2[0]+=h0*h0;  s1[1]+=h1; s2[1]+=h1*h1;
    s1[2]+=h2; s2[2]+=h2*h2;  s1[3]+=h3; s2[3]+=h3*h3;
  }
  __shared__ float red[4*DD];
  #pragma unroll
  for (int c=0;c<4;c++) red[wave*DD + lane*4 + c] = s1[c];
  __syncthreads();
  if (threadIdx.x < DD){
    float t = red[threadIdx.x] + red[DD+threadIdx.x] + red[2*DD+threadIdx.x] + red[3*DD+threadIdx.x];
    atomicAdd(&hsum[threadIdx.x], t);
  }
  __syncthreads();
  #pragma unroll
  for (int c=0;c<4;c++) red[wave*DD + lane*4 + c] = s2[c];
  __syncthreads();
  if (threadIdx.x < DD){
    float t = red[threadIdx.x] + red[DD+threadIdx.x] + red[2*DD+threadIdx.x] + red[3*DD+threadIdx.x];
    atomicAdd(&hsumsq[threadIdx.x], t);
  }
}

// ---------------- graph kernel: list loops unrolled x4 (gather MLP) ----------------
__global__ __launch_bounds__(256) void k_graph(
    const unsigned short* __restrict__ Gh, const unsigned short* __restrict__ He,
    const unsigned short* __restrict__ Iu,
    const int* __restrict__ goffa, const int* __restrict__ alist,
    const int* __restrict__ goffb, const int* __restrict__ blist,
    float* __restrict__ u_pre)
{
  int g = blockIdx.x, t = threadIdx.x;
  int a0 = goffa[g], a1 = goffa[g+1];
  float sA = 0.f;
  {
    int i = a0;
    for (; i + 4 <= a1; i += 4){
      int r0 = alist[i], r1 = alist[i+1], r2 = alist[i+2], r3 = alist[i+3];
      float v0 = bf2f(Gh[(size_t)r0*DD + t]);
      float v1 = bf2f(Gh[(size_t)r1*DD + t]);
      float v2 = bf2f(Gh[(size_t)r2*DD + t]);
      float v3 = bf2f(Gh[(size_t)r3*DD + t]);
      sA += (v0 + v1) + (v2 + v3);
    }
    for (; i < a1; ++i) sA += bf2f(Gh[(size_t)alist[i]*DD + t]);
  }
  int b0 = goffb[g], b1 = goffb[g+1];
  float sB = 0.f;
  {
    int i = b0;
    for (; i + 4 <= b1; i += 4){
      int r0 = blist[i], r1 = blist[i+1], r2 = blist[i+2], r3 = blist[i+3];
      float v0 = bf2f(He[(size_t)r0*DD + t]);
      float v1 = bf2f(He[(size_t)r1*DD + t]);
      float v2 = bf2f(He[(size_t)r2*DD + t]);
      float v3 = bf2f(He[(size_t)r3*DD + t]);
      sB += (v0 + v1) + (v2 + v3);
    }
    for (; i < b1; ++i) sB += bf2f(He[(size_t)blist[i]*DD + t]);
  }
  float cA = (float)max(a1 - a0, 1);
  float cB = (float)max(b1 - b0, 1);
  u_pre[(size_t)g*DD + t] = sA/cA + sB/cB + bf2f(Iu[(size_t)g*DD + t]);
}

__global__ void k_ustats(const float* __restrict__ u_pre, float* usum, float* usumsq){
  int t = threadIdx.x;
  float s = 0.f, s2 = 0.f;
  for (int g = blockIdx.x; g < NG; g += gridDim.x){
    float v = u_pre[(size_t)g*DD + t];
    s += v; s2 += v*v;
  }
  atomicAdd(&usum[t], s);
  atomicAdd(&usumsq[t], s2);
}

// ---------------- BN finalize + normalize/ELU ----------------
__global__ void k_bnfin(const float* __restrict__ sums, const float* __restrict__ sumsq,
                        float* __restrict__ mr){
  int o = blockIdx.x, t = threadIdx.x;
  float n = (o==0) ? (float)NA : (o==1) ? (float)NB : (float)NG;
  float m = sums[o*DD+t]/n;
  float v = sumsq[o*DD+t]/n - m*m;
  mr[o*2*DD + t]      = m;
  mr[o*2*DD + DD + t] = rsqrtf(fmaxf(v, 0.f) + EPS_BN);
}

// normalize bf16 src -> fp32 dst (h, e)
__global__ __launch_bounds__(256) void k_norm_bf(
    const unsigned short* __restrict__ src, float* __restrict__ dst, size_t nrows,
    const float* __restrict__ mr, const float* __restrict__ gamma,
    const float* __restrict__ beta)
{
  __shared__ float sm[DD], sr[DD], sg[DD], sb[DD];
  int t = threadIdx.x;
  sm[t] = mr[t]; sr[t] = mr[DD+t]; sg[t] = gamma[t]; sb[t] = beta[t];
  __syncthreads();
  size_t total = nrows*(DD/4);
  for (size_t i = blockIdx.x*(size_t)blockDim.x + t; i < total;
       i += (size_t)gridDim.x*blockDim.x){
    int c = ((int)(i & 63))*4;
    ushort4 s = ((const ushort4*)src)[i];
    float z0 = (bf2f(s.x) - sm[c+0])*sr[c+0]*sg[c+0] + sb[c+0];
    float z1 = (bf2f(s.y) - sm[c+1])*sr[c+1]*sg[c+1] + sb[c+1];
    float z2 = (bf2f(s.z) - sm[c+2])*sr[c+2]*sg[c+2] + sb[c+2];
    float z3 = (bf2f(s.w) - sm[c+3])*sr[c+3]*sg[c+3] + sb[c+3];
    float4 v;
    v.x = z0 > 0.f ? z0 : expm1f(z0);
    v.y = z1 > 0.f ? z1 : expm1f(z1);
    v.z = z2 > 0.f ? z2 : expm1f(z2);
    v.w = z3 > 0.f ? z3 : expm1f(z3);
    ((float4*)dst)[i] = v;
  }
}

// normalize fp32 in-place (u)
__global__ __launch_bounds__(256) void k_norm_f32(
    float* __restrict__ buf, size_t nrows,
    const float* __restrict__ mr, const float* __restrict__ gamma,
    const float* __restrict__ beta)
{
  __shared__ float sm[DD], sr[DD], sg[DD], sb[DD];
  int t = threadIdx.x;
  sm[t] = mr[t]; sr[t] = mr[DD+t]; sg[t] = gamma[t]; sb[t] = beta[t];
  __syncthreads();
  size_t total = nrows*(DD/4);
  for (size_t i = blockIdx.x*(size_t)blockDim.x + t; i < total;
       i += (size_t)gridDim.x*blockDim.x){
    int c = ((int)(i & 63))*4;
    float4 v = ((float4*)buf)[i];
    float z0 = (v.x - sm[c+0])*sr[c+0]*sg[c+0] + sb[c+0];
    float z1 = (v.y - sm[c+1])*sr[c+1]*sg[c+1] + sb[c+1];
    float z2 = (v.z - sm[c+2])*sr[c+2]*sg[c+2] + sb[c+2];
    float z3 = (v.w - sm[c+3])*sr[c+3]*sg[c+3] + sb[c+3];
    v.x = z0 > 0.f ? z0 : expm1f(z0);
    v.y = z1 > 0.f ? z1 : expm1f(z1);
    v.z = z2 > 0.f ? z2 : expm1f(z2);
    v.w = z3 > 0.f ? z3 : expm1f(z3);
    ((float4*)buf)[i] = v;
  }
}

// ================================ launcher =================================
extern "C" void kernel_launch(void* const* d_in, const int* in_sizes, int n_in,
                              void* d_out, int out_size, void* d_ws, size_t ws_size,
                              hipStream_t stream)
{
  (void)in_sizes; (void)n_in; (void)out_size;
  const float* h   = (const float*)d_in[0];
  const float* e   = (const float*)d_in[1];
  const float* u   = (const float*)d_in[2];
  const float* snn = (const float*)d_in[3];
  const float* sne = (const float*)d_in[4];
  const float* W   = (const float*)d_in[5];
  const float* b   = (const float*)d_in[6];
  const float* gamma = (const float*)d_in[7];
  const float* beta  = (const float*)d_in[8];
  const int* ba  = (const int*)d_in[9];
  const int* a2g = (const int*)d_in[10];
  const int* b2g = (const int*)d_in[11];

  float* outp  = (float*)d_out;
  float* h_out = outp;
  float* e_out = outp + (size_t)NA*DD;
  float* u_pre = outp + (size_t)(NA+NB)*DD;

  char* ws = (char*)d_ws;
  size_t off = 0;
  auto alloc = [&](size_t bytes)->char* {
    char* p = ws + off;
    off += (bytes + 255) & ~(size_t)255;
    return p;
  };
  unsigned short* Wbf = (unsigned short*)alloc((size_t)9*DD*DD*2);
  unsigned short* Yh  = (unsigned short*)alloc((size_t)4*NA*DD*2);
  unsigned short* Ye  = (unsigned short*)alloc((size_t)2*NB*DD*2);
  unsigned short* Yu  = (unsigned short*)alloc((size_t)3*NG*DD*2);
  unsigned short* Sg  = (unsigned short*)alloc((size_t)NB*DD*2);
  int* aoff  = (int*)alloc((size_t)(NA+1)*4);
  int* goffa = (int*)alloc((size_t)(NG+1)*4);
  int* goffb = (int*)alloc((size_t)(NG+1)*4);
  int* alist = (int*)alloc((size_t)NA*4);
  int* blist = (int*)alloc((size_t)NB*4);
  int* incb  = (int*)alloc((size_t)2*NB*4);
  int* inco  = (int*)alloc((size_t)2*NB*4);
  int* part  = (int*)alloc(1024);
  float* mr  = (float*)alloc((size_t)3*2*DD*4);
  char* zz   = ws + off;                      // ---- zero zone start ----
  int* deg      = (int*)alloc((size_t)NA*4);
  int* cur_atom = (int*)alloc((size_t)NA*4);
  int* cnta  = (int*)alloc((size_t)NG*4);
  int* cntb  = (int*)alloc((size_t)NG*4);
  int* cura  = (int*)alloc((size_t)NG*4);
  int* curb  = (int*)alloc((size_t)NG*4);
  float* sums  = (float*)alloc((size_t)3*DD*4);
  float* sumsq = (float*)alloc((size_t)3*DD*4);
  size_t zbytes = (size_t)((ws + off) - zz);

  if (ws_size < off) return;

  unsigned short* Ah = Yh;
  unsigned short* Dh = Yh + (size_t)1*NA*DD;   // becomes bf16(h_pre) after k_atom
  unsigned short* Eh = Yh + (size_t)2*NA*DD;
  unsigned short* Gh = Yh + (size_t)3*NA*DD;
  unsigned short* Be = Ye;                     // becomes bf16(e_pre) after k_bond
  unsigned short* He = Ye + (size_t)NB*DD;
  unsigned short* Cu = Yu;
  unsigned short* Fu = Yu + (size_t)1*NG*DD;
  unsigned short* Iu = Yu + (size_t)2*NG*DD;

  k_zero<<<256, 256, 0, stream>>>((int4*)zz, zbytes/16);
  k_wconv<<<288, 256, 0, stream>>>(W, Wbf, 9*DD*DD/4);

  k_gemm8<<<(NA+95)/96, 512, 0, stream>>>(h, NA, Wbf, b, Yh, 0,3,4,6, 4);
  k_gemm8<<<(NB+95)/96, 512, 0, stream>>>(e, NB, Wbf, b, Ye, 1,7,0,0, 2);
  k_gemm8<<<(NG+95)/96, 512, 0, stream>>>(u, NG, Wbf, b, Yu, 2,5,8,0, 3);

  k_hist<<<1024, 256, 0, stream>>>(ba, b2g, a2g, deg, cntb, cnta);

  k_scan_partials<<<98, 256, 0, stream>>>(deg, NA, part);
  k_scan_small<<<1, 64, 0, stream>>>(part, 98);
  k_scan_final<<<98, 256, 0, stream>>>(deg, NA, part, aoff);
  k_scan_partials<<<5, 256, 0, stream>>>(cnta, NG, part);
  k_scan_small<<<1, 64, 0, stream>>>(part, 5);
  k_scan_final<<<5, 256, 0, stream>>>(cnta, NG, part, goffa);
  k_scan_partials<<<5, 256, 0, stream>>>(cntb, NG, part);
  k_scan_small<<<1, 64, 0, stream>>>(part, 5);
  k_scan_final<<<5, 256, 0, stream>>>(cntb, NG, part, goffb);

  k_scatter_atoms<<<512, 256, 0, stream>>>(a2g, goffa, cura, alist);
  k_scatter_bonds<<<512, 256, 0, stream>>>(ba, b2g, goffb, curb, blist,
                                           aoff, cur_atom, incb, inco);

  k_bond<<<2048, 256, 0, stream>>>(Ah, Be, Cu, ba, b2g, sne, Sg,
                                   sums + DD, sumsq + DD);
  k_atom<<<2048, 256, 0, stream>>>(Dh, Eh, Fu, Sg, aoff, incb, inco, a2g, snn,
                                   sums + 0, sumsq + 0);
  k_graph<<<NG, 256, 0, stream>>>(Gh, He, Iu, goffa, alist, goffb, blist, u_pre);
  k_ustats<<<40, 256, 0, stream>>>(u_pre, sums + 2*DD, sumsq + 2*DD);

  k_bnfin<<<3, 256, 0, stream>>>(sums, sumsq, mr);

  k_norm_bf<<<2048, 256, 0, stream>>>(Dh, h_out, (size_t)NA, mr + 0,    gamma + 0,    beta + 0);
  k_norm_bf<<<2048, 256, 0, stream>>>(Be, e_out, (size_t)NB, mr + 2*DD, gamma + DD,   beta + DD);
  k_norm_f32<<<64,  256, 0, stream>>>(u_pre, (size_t)NG, mr + 4*DD,     gamma + 2*DD, beta + 2*DD);
}